// Round 16
// baseline (431.697 us; speedup 1.0000x reference)
//
#include <hip/hip_runtime.h>
#include <cstddef>

#define LN_EPS 1e-5f
typedef unsigned short u16;
typedef unsigned int u32;
typedef __attribute__((ext_vector_type(8))) short bf16x8;
typedef __attribute__((ext_vector_type(4))) float f32x4;

constexpr int SCAN_T = 256, SCAN_V = 8, SCAN_ELEMS = SCAN_T * SCAN_V;
constexpr int KP = 136;   // LDS stride (elems): 272B row stride

__device__ inline u16 f2bf(float f) {
    u32 u = __float_as_uint(f);
    u += 0x7FFFu + ((u >> 16) & 1u);
    return (u16)(u >> 16);
}
__device__ inline float bf2f(u16 h) { return __uint_as_float((u32)h << 16); }

__device__ inline void acc_u4(float* a, uint4 u) {
    a[0] += bf2f((u16)(u.x & 0xFFFF)); a[1] += bf2f((u16)(u.x >> 16));
    a[2] += bf2f((u16)(u.y & 0xFFFF)); a[3] += bf2f((u16)(u.y >> 16));
    a[4] += bf2f((u16)(u.z & 0xFFFF)); a[5] += bf2f((u16)(u.z >> 16));
    a[6] += bf2f((u16)(u.w & 0xFFFF)); a[7] += bf2f((u16)(u.w >> 16));
}

// ---------------- degree / inverse degree ----------------
__global__ __launch_bounds__(256) void k_deg(const int* __restrict__ rows,
                                             int* __restrict__ deg, int E) {
    int e = blockIdx.x * 256 + threadIdx.x;
    if (e < E) atomicAdd(&deg[rows[e]], 1);
}

__global__ __launch_bounds__(256) void k_invdeg(const int* __restrict__ deg,
                                                float* __restrict__ invdeg, int N) {
    int i = blockIdx.x * 256 + threadIdx.x;
    if (i < N) invdeg[i] = 1.0f / (float)max(deg[i], 1);
}

// ---------------- CSR build ----------------
__global__ __launch_bounds__(SCAN_T) void k_scan1(const int* __restrict__ deg,
                                                  int* __restrict__ row_ptr,
                                                  int* __restrict__ bsum, int N) {
    __shared__ int ts[SCAN_T];
    int t = threadIdx.x;
    int base = blockIdx.x * SCAN_ELEMS;
    int v[SCAN_V];
    int s = 0;
    #pragma unroll
    for (int j = 0; j < SCAN_V; ++j) {
        int i = base + t * SCAN_V + j;
        v[j] = (i < N) ? deg[i] : 0;
        s += v[j];
    }
    ts[t] = s;
    __syncthreads();
    for (int off = 1; off < SCAN_T; off <<= 1) {
        int val = (t >= off) ? ts[t - off] : 0;
        __syncthreads();
        ts[t] += val;
        __syncthreads();
    }
    int excl = (t > 0) ? ts[t - 1] : 0;
    #pragma unroll
    for (int j = 0; j < SCAN_V; ++j) {
        int i = base + t * SCAN_V + j;
        if (i < N) row_ptr[i] = excl;
        excl += v[j];
    }
    if (t == SCAN_T - 1) bsum[blockIdx.x] = ts[SCAN_T - 1];
}

__global__ void k_scan2(int* __restrict__ bsum, int nb, int* __restrict__ row_ptr, int N) {
    int run = 0;
    for (int i = 0; i < nb; ++i) {
        int v = bsum[i];
        bsum[i] = run;
        run += v;
    }
    row_ptr[N] = run;
}

__global__ __launch_bounds__(SCAN_T) void k_scan3(int* __restrict__ row_ptr,
                                                  const int* __restrict__ bsum, int N) {
    int add = bsum[blockIdx.x];
    int base = blockIdx.x * SCAN_ELEMS;
    #pragma unroll
    for (int j = 0; j < SCAN_V; ++j) {
        int i = base + threadIdx.x * SCAN_V + j;
        if (i < N) row_ptr[i] += add;
    }
}

__global__ __launch_bounds__(256) void k_copy_cursor(const int* __restrict__ row_ptr,
                                                     int* __restrict__ cursor, int N) {
    int i = blockIdx.x * 256 + threadIdx.x;
    if (i < N) cursor[i] = row_ptr[i];
}

__global__ __launch_bounds__(256) void k_bucket(const int* __restrict__ rows,
                                                const int* __restrict__ cols,
                                                int* __restrict__ cursor,
                                                int* __restrict__ col_sorted, int E) {
    int e = blockIdx.x * 256 + threadIdx.x;
    if (e < E) {
        int r = rows[e];
        int pos = atomicAdd(&cursor[r], 1);
        col_sorted[pos] = cols[e];
    }
}

// ---------------- weight prep ----------------
// Wt layout [128 cols][128 k] bf16
// Wt_in: k=0 zero (feat0 weight dropped), k=1..127 = W_in[31+k][c]
__global__ __launch_bounds__(256) void k_wprep(const float* __restrict__ W_in,
                                               const float* __restrict__ msg_W,
                                               u16* __restrict__ Wt_in,
                                               u16* __restrict__ Wt_msg) {
    int idx = blockIdx.x * 256 + threadIdx.x;
    const int t1 = 128 * 128;
    if (idx < t1) {
        int c = idx >> 7, k = idx & 127;
        float v = (k >= 1) ? W_in[(31 + k) * 128 + c] : 0.f;
        Wt_in[idx] = f2bf(v);
    } else {
        idx -= t1;
        if (idx < 3 * 128 * 128) {
            int l = idx / (128 * 128);
            int r = idx & (128 * 128 - 1);
            int c = r >> 7, k = r & 127;
            Wt_msg[idx] = f2bf(msg_W[l * 16384 + k * 128 + c]);
        }
    }
}

// E_proj[op][c] = sum_j emb[op][j] * W_in[j][c]
__global__ __launch_bounds__(128) void k_eproj(const float* __restrict__ W_in,
                                               const float* __restrict__ emb,
                                               float* __restrict__ E_proj) {
    __shared__ float es[32];
    int op = blockIdx.x, c = threadIdx.x;
    if (c < 32) es[c] = emb[op * 32 + c];
    __syncthreads();
    float s = 0.f;
    #pragma unroll
    for (int j = 0; j < 32; ++j) s = fmaf(es[j], W_in[j * 128 + c], s);
    E_proj[op * 128 + c] = s;
}

// -- input layer: 256 thr / 4 waves, wave-private 16-row tiles, barrier-free --
__global__ __launch_bounds__(256) void k_input_mfma(
    const float* __restrict__ features, const float* __restrict__ E_proj,
    const u16* __restrict__ Wt,
    const float* __restrict__ bias, const float* __restrict__ gain,
    const float* __restrict__ beta, u16* __restrict__ x, int N, int ntiles)
{
    __shared__ u16 A[64 * KP];
    __shared__ u16 Wl[128 * KP];
    __shared__ int ops[64];
    const int tid = threadIdx.x;
    const int lane = tid & 63, w = tid >> 6;
    const int l15 = lane & 15;
    const int kq = (lane >> 4) * 8;
    const int r = tid >> 2, q = tid & 3;   // rows 16w..16w+15: wave-private

    // stage W^T once per block (re-stride 128 -> KP); only cross-wave dependency
    for (int i = tid; i < 2048; i += 256) {
        uint4 v = ((const uint4*)Wt)[i];
        *(uint4*)&Wl[(i >> 4) * KP + (i & 15) * 8] = v;
    }
    float bsr[8], gsr[8], btr[8];
    #pragma unroll
    for (int t = 0; t < 8; ++t) {
        int col = t * 16 + l15;
        bsr[t] = bias[col]; gsr[t] = gain[col]; btr[t] = beta[col];
    }
    __syncthreads();   // Wl ready; no further barriers (tiles wave-private)

    for (int tile = blockIdx.x; tile < ntiles; tile += gridDim.x) {
        const int node0 = tile * 32;
        {
            int nl = r >> 1, b = r & 1;
            int node = min(node0 + nl, N - 1);
            const float* fr = features + ((size_t)b * N + node) * 128 + q * 32;
            u32 pk[16];
            float4 v0 = ((const float4*)fr)[0];
            if (q == 0) {
                int op = (int)v0.x;
                op = op < 0 ? 0 : (op > 127 ? 127 : op);
                ops[r] = op;
            }
            pk[0] = (u32)f2bf(v0.x) | ((u32)f2bf(v0.y) << 16);
            pk[1] = (u32)f2bf(v0.z) | ((u32)f2bf(v0.w) << 16);
            #pragma unroll
            for (int j = 1; j < 8; ++j) {
                float4 v = ((const float4*)fr)[j];
                pk[2 * j]     = (u32)f2bf(v.x) | ((u32)f2bf(v.y) << 16);
                pk[2 * j + 1] = (u32)f2bf(v.z) | ((u32)f2bf(v.w) << 16);
            }
            uint4* dst = (uint4*)&A[r * KP + q * 32];
            #pragma unroll
            for (int j = 0; j < 4; ++j)
                dst[j] = make_uint4(pk[4 * j], pk[4 * j + 1], pk[4 * j + 2], pk[4 * j + 3]);
        }
        // wave-synchronous: compiler orders ds_write -> ds_read via lgkmcnt

        const int arow = w * 16 + l15;
        bf16x8 a[4];
        #pragma unroll
        for (int kt = 0; kt < 4; ++kt)
            a[kt] = *(const bf16x8*)&A[arow * KP + kt * 32 + kq];
        f32x4 acc[8];
        #pragma unroll
        for (int t = 0; t < 8; ++t) {
            f32x4 c4 = {0.f, 0.f, 0.f, 0.f};
            #pragma unroll
            for (int kt = 0; kt < 4; ++kt) {
                bf16x8 b = *(const bf16x8*)&Wl[(t * 16 + l15) * KP + kt * 32 + kq];
                c4 = __builtin_amdgcn_mfma_f32_16x16x32_bf16(a[kt], b, c4, 0, 0, 0);
            }
            acc[t] = c4;
        }

        int opr[4];
        #pragma unroll
        for (int i = 0; i < 4; ++i) opr[i] = ops[w * 16 + (lane >> 4) * 4 + i];

        float s[4] = {0, 0, 0, 0}, sq[4] = {0, 0, 0, 0};
        #pragma unroll
        for (int t = 0; t < 8; ++t) {
            int col = t * 16 + l15;
            #pragma unroll
            for (int i = 0; i < 4; ++i) {
                float aY = acc[t][i] + bsr[t] + E_proj[opr[i] * 128 + col];
                float y = aY / (1.0f + __expf(-aY));
                acc[t][i] = y;
                s[i] += y;
                sq[i] = fmaf(y, y, sq[i]);
            }
        }
        #pragma unroll
        for (int m = 1; m <= 8; m <<= 1) {
            #pragma unroll
            for (int i = 0; i < 4; ++i) {
                s[i] += __shfl_xor(s[i], m);
                sq[i] += __shfl_xor(sq[i], m);
            }
        }
        #pragma unroll
        for (int i = 0; i < 4; ++i) {
            float mu = s[i] * (1.0f / 128.0f);
            float var = sq[i] * (1.0f / 128.0f) - mu * mu;
            float inv = rsqrtf(var + LN_EPS);
            int rr = w * 16 + (lane >> 4) * 4 + i;
            if (node0 + (rr >> 1) < N) {
                u16* xr = x + ((size_t)node0 * 2 + rr) * 128;
                #pragma unroll
                for (int t = 0; t < 8; ++t)
                    xr[t * 16 + l15] = f2bf((acc[t][i] - mu) * inv * gsr[t] + btr[t]);
            }
        }
    }
}

// -- fused mp layer: 256 thr / 4 waves, wave-private tiles, barrier-free ------
__global__ __launch_bounds__(256) void k_mp_mfma(
    const int* __restrict__ row_ptr, const int* __restrict__ col_sorted,
    const float* __restrict__ invdeg, const u16* __restrict__ xin,
    const u16* __restrict__ Wt, const float* __restrict__ bias,
    const float* __restrict__ gain, const float* __restrict__ beta,
    u16* __restrict__ xout, int N, int ntiles)
{
    __shared__ u16 A[64 * KP];
    __shared__ u16 Wl[128 * KP];
    const int tid = threadIdx.x;
    const int lane = tid & 63, w = tid >> 6;
    const int l15 = lane & 15;
    const int kq = (lane >> 4) * 8;
    const int r = tid >> 2, q = tid & 3;   // rows 16w..16w+15: wave-private

    // stage W^T once per block (re-stride 128 -> KP)
    for (int i = tid; i < 2048; i += 256) {
        uint4 v = ((const uint4*)Wt)[i];
        *(uint4*)&Wl[(i >> 4) * KP + (i & 15) * 8] = v;
    }
    float bsr[8], gsr[8], btr[8];
    #pragma unroll
    for (int t = 0; t < 8; ++t) {
        int col = t * 16 + l15;
        bsr[t] = bias[col]; gsr[t] = gain[col]; btr[t] = beta[col];
    }
    __syncthreads();   // Wl ready; no further barriers (tiles wave-private)

    for (int tile = blockIdx.x; tile < ntiles; tile += gridDim.x) {
        const int node0 = tile * 32;
        // gather: 4 threads per (node,b) row, 64B contiguous each, 2-edge unroll
        {
            int nl = r >> 1, b = r & 1;
            int node = min(node0 + nl, N - 1);
            int e0 = row_ptr[node], e1 = row_ptr[node + 1];
            float sc = invdeg[node];
            const u32* xb = (const u32*)xin + (size_t)b * 64 + q * 16;
            float fa[32];
            #pragma unroll
            for (int j = 0; j < 32; ++j) fa[j] = 0.f;
            int e = e0;
            for (; e + 2 <= e1; e += 2) {
                int c0 = col_sorted[e], c1 = col_sorted[e + 1];
                const uint4* p0 = (const uint4*)(xb + (size_t)c0 * 128);
                const uint4* p1 = (const uint4*)(xb + (size_t)c1 * 128);
                uint4 u0 = p0[0], u1 = p0[1], u2 = p0[2], u3 = p0[3];
                uint4 w0 = p1[0], w1 = p1[1], w2 = p1[2], w3 = p1[3];
                acc_u4(fa + 0, u0);  acc_u4(fa + 8, u1);
                acc_u4(fa + 16, u2); acc_u4(fa + 24, u3);
                acc_u4(fa + 0, w0);  acc_u4(fa + 8, w1);
                acc_u4(fa + 16, w2); acc_u4(fa + 24, w3);
            }
            if (e < e1) {
                const uint4* p0 = (const uint4*)(xb + (size_t)col_sorted[e] * 128);
                uint4 u0 = p0[0], u1 = p0[1], u2 = p0[2], u3 = p0[3];
                acc_u4(fa + 0, u0);  acc_u4(fa + 8, u1);
                acc_u4(fa + 16, u2); acc_u4(fa + 24, u3);
            }
            u32 pk[16];
            #pragma unroll
            for (int j = 0; j < 16; ++j)
                pk[j] = (u32)f2bf(fa[2 * j] * sc) | ((u32)f2bf(fa[2 * j + 1] * sc) << 16);
            uint4* dst = (uint4*)&A[r * KP + q * 32];
            #pragma unroll
            for (int j = 0; j < 4; ++j)
                dst[j] = make_uint4(pk[4 * j], pk[4 * j + 1], pk[4 * j + 2], pk[4 * j + 3]);
        }
        // wave-synchronous: no barrier

        const int arow = w * 16 + l15;
        bf16x8 a[4];
        #pragma unroll
        for (int kt = 0; kt < 4; ++kt)
            a[kt] = *(const bf16x8*)&A[arow * KP + kt * 32 + kq];
        f32x4 acc[8];
        #pragma unroll
        for (int t = 0; t < 8; ++t) {
            f32x4 c4 = {0.f, 0.f, 0.f, 0.f};
            #pragma unroll
            for (int kt = 0; kt < 4; ++kt) {
                bf16x8 bfr = *(const bf16x8*)&Wl[(t * 16 + l15) * KP + kt * 32 + kq];
                c4 = __builtin_amdgcn_mfma_f32_16x16x32_bf16(a[kt], bfr, c4, 0, 0, 0);
            }
            acc[t] = c4;
        }

        float s[4] = {0, 0, 0, 0}, sq[4] = {0, 0, 0, 0};
        #pragma unroll
        for (int t = 0; t < 8; ++t) {
            #pragma unroll
            for (int i = 0; i < 4; ++i) {
                float aY = acc[t][i] + bsr[t];
                float y = aY / (1.0f + __expf(-aY));
                acc[t][i] = y;
                s[i] += y;
                sq[i] = fmaf(y, y, sq[i]);
            }
        }
        #pragma unroll
        for (int m = 1; m <= 8; m <<= 1) {
            #pragma unroll
            for (int i = 0; i < 4; ++i) {
                s[i] += __shfl_xor(s[i], m);
                sq[i] += __shfl_xor(sq[i], m);
            }
        }
        #pragma unroll
        for (int i = 0; i < 4; ++i) {
            float mu = s[i] * (1.0f / 128.0f);
            float var = sq[i] * (1.0f / 128.0f) - mu * mu;
            float inv = rsqrtf(var + LN_EPS);
            int rr = w * 16 + (lane >> 4) * 4 + i;
            if (node0 + (rr >> 1) < N) {
                u16* xr = xout + ((size_t)node0 * 2 + rr) * 128;
                #pragma unroll
                for (int t = 0; t < 8; ++t)
                    xr[t * 16 + l15] = f2bf((acc[t][i] - mu) * inv * gsr[t] + btr[t]);
            }
        }
    }
}

// ---------------- pooling (interleaved x) ----------------
__global__ __launch_bounds__(64) void k_pool(
    const u16* __restrict__ x, const int* __restrict__ lengths,
    float* __restrict__ pooled, int N, int B, int G, int SPLIT)
{
    int blk = blockIdx.x;
    int split = blk % SPLIT;
    int gb = blk / SPLIT;
    int b = gb % B, g = gb / B;
    int lane = threadIdx.x;
    int start = 0;
    for (int i = 0; i < g; ++i) start += lengths[i];
    int len = lengths[g];
    int chunk = (len + SPLIT - 1) / SPLIT;
    int n0 = start + split * chunk;
    int n1 = min(start + len, n0 + chunk);
    const u32* xb = (const u32*)x + (size_t)b * 64;
    float sx = 0.f, sy = 0.f;
    int n = n0;
    for (; n + 4 <= n1; n += 4) {
        u32 v0 = xb[(size_t)(n + 0) * 128 + lane];
        u32 v1 = xb[(size_t)(n + 1) * 128 + lane];
        u32 v2 = xb[(size_t)(n + 2) * 128 + lane];
        u32 v3 = xb[(size_t)(n + 3) * 128 + lane];
        sx += bf2f((u16)(v0 & 0xFFFF)) + bf2f((u16)(v1 & 0xFFFF)) +
              bf2f((u16)(v2 & 0xFFFF)) + bf2f((u16)(v3 & 0xFFFF));
        sy += bf2f((u16)(v0 >> 16)) + bf2f((u16)(v1 >> 16)) +
              bf2f((u16)(v2 >> 16)) + bf2f((u16)(v3 >> 16));
    }
    for (; n < n1; ++n) {
        u32 v = xb[(size_t)n * 128 + lane];
        sx += bf2f((u16)(v & 0xFFFF));
        sy += bf2f((u16)(v >> 16));
    }
    if (n1 > n0) {
        atomicAdd(&pooled[(g * B + b) * 128 + lane * 2 + 0], sx);
        atomicAdd(&pooled[(g * B + b) * 128 + lane * 2 + 1], sy);
    }
}

__global__ __launch_bounds__(128) void k_proj(
    const float* __restrict__ pooled, const float* __restrict__ Wp,
    const float* __restrict__ bp, float* __restrict__ out, int GB)
{
    int gb = blockIdx.x;
    int tid = threadIdx.x;
    float v = pooled[gb * 128 + tid] * Wp[tid];
    v += __shfl_down(v, 32);
    v += __shfl_down(v, 16);
    v += __shfl_down(v, 8);
    v += __shfl_down(v, 4);
    v += __shfl_down(v, 2);
    v += __shfl_down(v, 1);
    __shared__ float red[2];
    if ((tid & 63) == 0) red[tid >> 6] = v;
    __syncthreads();
    if (tid == 0) out[gb] = red[0] + red[1] + bp[0];
}

// ---------------- host ----------------
extern "C" void kernel_launch(void* const* d_in, const int* in_sizes, int n_in,
                              void* d_out, int out_size, void* d_ws, size_t ws_size,
                              hipStream_t stream) {
    const float* features = (const float*)d_in[0];
    const int* edge_index = (const int*)d_in[1];
    const int* lengths    = (const int*)d_in[2];
    const float* emb      = (const float*)d_in[3];
    const float* W_in     = (const float*)d_in[4];
    const float* b_in     = (const float*)d_in[5];
    const float* g_in     = (const float*)d_in[6];
    const float* beta_in  = (const float*)d_in[7];
    const float* msg_W    = (const float*)d_in[8];
    const float* msg_b    = (const float*)d_in[9];
    const float* msg_g    = (const float*)d_in[10];
    const float* msg_beta = (const float*)d_in[11];
    const float* W_proj   = (const float*)d_in[12];
    const float* b_proj   = (const float*)d_in[13];
    float* out = (float*)d_out;

    const int E = in_sizes[1] / 2;
    const int G = in_sizes[2];
    const int B = out_size / G;
    const int C = in_sizes[5];           // 128
    const int F = 128;
    const int N = in_sizes[0] / (B * F);
    const int M = B * N;
    const int L = in_sizes[9] / C;       // 3

    const int* rows = edge_index;
    const int* cols = edge_index + E;

    // workspace carve-up (16B-aligned)
    u16* buf0   = (u16*)d_ws;                               // M*128 (interleaved [n][b][c])
    u16* buf1   = buf0 + (size_t)M * 128;                   // M*128
    u16* Wt_in  = buf1 + (size_t)M * 128;                   // 128*128
    u16* Wt_msg = Wt_in + 128 * 128;                        // 3*128*128
    float* E_proj = (float*)(Wt_msg + 3 * 128 * 128);       // 128*128 f32
    float* invdeg = E_proj + 128 * 128;                     // N
    int*   deg    = (int*)(invdeg + N);                     // N (reused as cursor)
    float* pooled = (float*)(deg + N);                      // G*B*128
    int*   row_ptr = (int*)(pooled + (size_t)G * B * 128);  // N+1
    int*   col_sorted = row_ptr + N + 1;                    // E
    int*   bsum   = col_sorted + E;

    const int nb_scan = (N + SCAN_ELEMS - 1) / SCAN_ELEMS;
    const int nt32 = (N + 31) / 32;
    const int grid_mp = nt32 < 768 ? nt32 : 768;

    // weight prep
    {
        int total = 4 * 128 * 128;
        k_wprep<<<(total + 255) / 256, 256, 0, stream>>>(W_in, msg_W, Wt_in, Wt_msg);
        k_eproj<<<128, 128, 0, stream>>>(W_in, emb, E_proj);
    }

    // degree + CSR
    hipMemsetAsync(deg, 0, (size_t)N * sizeof(int), stream);
    k_deg<<<(E + 255) / 256, 256, 0, stream>>>(rows, deg, E);
    k_invdeg<<<(N + 255) / 256, 256, 0, stream>>>(deg, invdeg, N);
    k_scan1<<<nb_scan, SCAN_T, 0, stream>>>(deg, row_ptr, bsum, N);
    k_scan2<<<1, 1, 0, stream>>>(bsum, nb_scan, row_ptr, N);
    k_scan3<<<nb_scan, SCAN_T, 0, stream>>>(row_ptr, bsum, N);
    k_copy_cursor<<<(N + 255) / 256, 256, 0, stream>>>(row_ptr, deg, N);
    k_bucket<<<(E + 255) / 256, 256, 0, stream>>>(rows, cols, deg, col_sorted, E);

    // input layer -> buf0 (interleaved)
    k_input_mfma<<<grid_mp, 256, 0, stream>>>(features, E_proj, Wt_in,
                                              b_in, g_in, beta_in, buf0, N, nt32);

    // fused mp layers (ping-pong)
    u16* bufs[2] = {buf0, buf1};
    int cur = 0;
    for (int l = 0; l < L; ++l) {
        k_mp_mfma<<<grid_mp, 256, 0, stream>>>(row_ptr, col_sorted, invdeg,
                                               bufs[cur], Wt_msg + (size_t)l * 128 * 128,
                                               msg_b + (size_t)l * C, msg_g + (size_t)l * C,
                                               msg_beta + (size_t)l * C,
                                               bufs[1 - cur], N, nt32);
        cur = 1 - cur;
    }

    // pooling + projection
    const int SPLIT = 128;
    hipMemsetAsync(pooled, 0, (size_t)G * B * 128 * sizeof(float), stream);
    k_pool<<<G * B * SPLIT, 64, 0, stream>>>(bufs[cur], lengths, pooled, N, B, G, SPLIT);
    k_proj<<<G * B, 128, 0, stream>>>(pooled, W_proj, b_proj, out, G * B);
}

// Round 17
// 413.902 us; speedup vs baseline: 1.0430x; 1.0430x over previous
//
#include <hip/hip_runtime.h>
#include <cstddef>

#define LN_EPS 1e-5f
typedef unsigned short u16;
typedef unsigned int u32;
typedef __attribute__((ext_vector_type(8))) short bf16x8;
typedef __attribute__((ext_vector_type(4))) float f32x4;

constexpr int SCAN_T = 256, SCAN_V = 8, SCAN_ELEMS = SCAN_T * SCAN_V;
constexpr int KP = 136;   // LDS stride (elems): 272B row stride

__device__ inline u16 f2bf(float f) {
    u32 u = __float_as_uint(f);
    u += 0x7FFFu + ((u >> 16) & 1u);
    return (u16)(u >> 16);
}
__device__ inline float bf2f(u16 h) { return __uint_as_float((u32)h << 16); }

__device__ inline void acc_u4(float* a, uint4 u) {
    a[0] += bf2f((u16)(u.x & 0xFFFF)); a[1] += bf2f((u16)(u.x >> 16));
    a[2] += bf2f((u16)(u.y & 0xFFFF)); a[3] += bf2f((u16)(u.y >> 16));
    a[4] += bf2f((u16)(u.z & 0xFFFF)); a[5] += bf2f((u16)(u.z >> 16));
    a[6] += bf2f((u16)(u.w & 0xFFFF)); a[7] += bf2f((u16)(u.w >> 16));
}

// ---------------- degree / inverse degree ----------------
__global__ __launch_bounds__(256) void k_deg(const int* __restrict__ rows,
                                             int* __restrict__ deg, int E) {
    int e = blockIdx.x * 256 + threadIdx.x;
    if (e < E) atomicAdd(&deg[rows[e]], 1);
}

__global__ __launch_bounds__(256) void k_invdeg(const int* __restrict__ deg,
                                                float* __restrict__ invdeg, int N) {
    int i = blockIdx.x * 256 + threadIdx.x;
    if (i < N) invdeg[i] = 1.0f / (float)max(deg[i], 1);
}

// ---------------- group map ----------------
__global__ void k_gstart(const int* __restrict__ lengths, int* __restrict__ gstart, int G) {
    int run = 0;
    for (int i = 0; i < G; ++i) { gstart[i] = run; run += lengths[i]; }
    gstart[G] = run;
}

__global__ __launch_bounds__(256) void k_grp(const int* __restrict__ gstart,
                                             int* __restrict__ grp, int N, int G) {
    int i = blockIdx.x * 256 + threadIdx.x;
    if (i < N) {
        int g = 0;
        while (g + 1 < G && i >= gstart[g + 1]) ++g;
        grp[i] = g;
    }
}

// ---------------- CSR build ----------------
__global__ __launch_bounds__(SCAN_T) void k_scan1(const int* __restrict__ deg,
                                                  int* __restrict__ row_ptr,
                                                  int* __restrict__ bsum, int N) {
    __shared__ int ts[SCAN_T];
    int t = threadIdx.x;
    int base = blockIdx.x * SCAN_ELEMS;
    int v[SCAN_V];
    int s = 0;
    #pragma unroll
    for (int j = 0; j < SCAN_V; ++j) {
        int i = base + t * SCAN_V + j;
        v[j] = (i < N) ? deg[i] : 0;
        s += v[j];
    }
    ts[t] = s;
    __syncthreads();
    for (int off = 1; off < SCAN_T; off <<= 1) {
        int val = (t >= off) ? ts[t - off] : 0;
        __syncthreads();
        ts[t] += val;
        __syncthreads();
    }
    int excl = (t > 0) ? ts[t - 1] : 0;
    #pragma unroll
    for (int j = 0; j < SCAN_V; ++j) {
        int i = base + t * SCAN_V + j;
        if (i < N) row_ptr[i] = excl;
        excl += v[j];
    }
    if (t == SCAN_T - 1) bsum[blockIdx.x] = ts[SCAN_T - 1];
}

__global__ void k_scan2(int* __restrict__ bsum, int nb, int* __restrict__ row_ptr, int N) {
    int run = 0;
    for (int i = 0; i < nb; ++i) {
        int v = bsum[i];
        bsum[i] = run;
        run += v;
    }
    row_ptr[N] = run;
}

__global__ __launch_bounds__(SCAN_T) void k_scan3(int* __restrict__ row_ptr,
                                                  const int* __restrict__ bsum, int N) {
    int add = bsum[blockIdx.x];
    int base = blockIdx.x * SCAN_ELEMS;
    #pragma unroll
    for (int j = 0; j < SCAN_V; ++j) {
        int i = base + threadIdx.x * SCAN_V + j;
        if (i < N) row_ptr[i] += add;
    }
}

__global__ __launch_bounds__(256) void k_copy_cursor(const int* __restrict__ row_ptr,
                                                     int* __restrict__ cursor, int N) {
    int i = blockIdx.x * 256 + threadIdx.x;
    if (i < N) cursor[i] = row_ptr[i];
}

__global__ __launch_bounds__(256) void k_bucket(const int* __restrict__ rows,
                                                const int* __restrict__ cols,
                                                int* __restrict__ cursor,
                                                int* __restrict__ col_sorted, int E) {
    int e = blockIdx.x * 256 + threadIdx.x;
    if (e < E) {
        int r = rows[e];
        int pos = atomicAdd(&cursor[r], 1);
        col_sorted[pos] = cols[e];
    }
}

// ---------------- weight prep ----------------
__global__ __launch_bounds__(256) void k_wprep(const float* __restrict__ W_in,
                                               const float* __restrict__ msg_W,
                                               u16* __restrict__ Wt_in,
                                               u16* __restrict__ Wt_msg) {
    int idx = blockIdx.x * 256 + threadIdx.x;
    const int t1 = 128 * 128;
    if (idx < t1) {
        int c = idx >> 7, k = idx & 127;
        float v = (k >= 1) ? W_in[(31 + k) * 128 + c] : 0.f;
        Wt_in[idx] = f2bf(v);
    } else {
        idx -= t1;
        if (idx < 3 * 128 * 128) {
            int l = idx / (128 * 128);
            int r = idx & (128 * 128 - 1);
            int c = r >> 7, k = r & 127;
            Wt_msg[idx] = f2bf(msg_W[l * 16384 + k * 128 + c]);
        }
    }
}

// E_proj[op][c] = sum_j emb[op][j] * W_in[j][c]
__global__ __launch_bounds__(128) void k_eproj(const float* __restrict__ W_in,
                                               const float* __restrict__ emb,
                                               float* __restrict__ E_proj) {
    __shared__ float es[32];
    int op = blockIdx.x, c = threadIdx.x;
    if (c < 32) es[c] = emb[op * 32 + c];
    __syncthreads();
    float s = 0.f;
    #pragma unroll
    for (int j = 0; j < 32; ++j) s = fmaf(es[j], W_in[j * 128 + c], s);
    E_proj[op * 128 + c] = s;
}

// -- input layer: 512 threads / 8 waves share 64-row tile + Wl ----------------
__global__ __launch_bounds__(512) void k_input_mfma(
    const float* __restrict__ features, const float* __restrict__ E_proj,
    const u16* __restrict__ Wt,
    const float* __restrict__ bias, const float* __restrict__ gain,
    const float* __restrict__ beta, u16* __restrict__ x, int N, int ntiles)
{
    __shared__ u16 A[64 * KP];
    __shared__ u16 Wl[128 * KP];
    __shared__ int ops[64];
    __shared__ float pS[64][2], pQ[64][2];
    const int tid = threadIdx.x;
    const int lane = tid & 63, w = tid >> 6;
    const int l15 = lane & 15;
    const int kq = (lane >> 4) * 8;
    const int r = tid >> 3, sl = tid & 7;
    const int wr = w & 3, wc = w >> 2;

    for (int i = tid; i < 2048; i += 512) {
        uint4 v = ((const uint4*)Wt)[i];
        *(uint4*)&Wl[(i >> 4) * KP + (i & 15) * 8] = v;
    }

    for (int tile = blockIdx.x; tile < ntiles; tile += gridDim.x) {
        const int node0 = tile * 32;
        {
            int nl = r >> 1, b = r & 1;
            int node = min(node0 + nl, N - 1);
            const float* fr = features + ((size_t)b * N + node) * 128 + sl * 16;
            float4 v0 = ((const float4*)fr)[0];
            float4 v1 = ((const float4*)fr)[1];
            float4 v2 = ((const float4*)fr)[2];
            float4 v3 = ((const float4*)fr)[3];
            if (sl == 0) {
                int op = (int)v0.x;
                op = op < 0 ? 0 : (op > 127 ? 127 : op);
                ops[r] = op;
            }
            u32 pk[8];
            pk[0] = (u32)f2bf(v0.x) | ((u32)f2bf(v0.y) << 16);
            pk[1] = (u32)f2bf(v0.z) | ((u32)f2bf(v0.w) << 16);
            pk[2] = (u32)f2bf(v1.x) | ((u32)f2bf(v1.y) << 16);
            pk[3] = (u32)f2bf(v1.z) | ((u32)f2bf(v1.w) << 16);
            pk[4] = (u32)f2bf(v2.x) | ((u32)f2bf(v2.y) << 16);
            pk[5] = (u32)f2bf(v2.z) | ((u32)f2bf(v2.w) << 16);
            pk[6] = (u32)f2bf(v3.x) | ((u32)f2bf(v3.y) << 16);
            pk[7] = (u32)f2bf(v3.z) | ((u32)f2bf(v3.w) << 16);
            uint4* dst = (uint4*)&A[r * KP + sl * 16];
            dst[0] = make_uint4(pk[0], pk[1], pk[2], pk[3]);
            dst[1] = make_uint4(pk[4], pk[5], pk[6], pk[7]);
        }
        __syncthreads();

        const int arow = wr * 16 + l15;
        bf16x8 a[4];
        #pragma unroll
        for (int kt = 0; kt < 4; ++kt)
            a[kt] = *(const bf16x8*)&A[arow * KP + kt * 32 + kq];
        f32x4 acc[4];
        #pragma unroll
        for (int t = 0; t < 4; ++t) {
            int bcol = wc * 64 + t * 16 + l15;
            f32x4 c4 = {0.f, 0.f, 0.f, 0.f};
            #pragma unroll
            for (int kt = 0; kt < 4; ++kt) {
                bf16x8 b = *(const bf16x8*)&Wl[bcol * KP + kt * 32 + kq];
                c4 = __builtin_amdgcn_mfma_f32_16x16x32_bf16(a[kt], b, c4, 0, 0, 0);
            }
            acc[t] = c4;
        }

        int opr[4];
        #pragma unroll
        for (int i = 0; i < 4; ++i) opr[i] = ops[wr * 16 + (lane >> 4) * 4 + i];

        float s[4] = {0, 0, 0, 0}, sq[4] = {0, 0, 0, 0};
        #pragma unroll
        for (int t = 0; t < 4; ++t) {
            int col = wc * 64 + t * 16 + l15;
            float bt = bias[col];
            #pragma unroll
            for (int i = 0; i < 4; ++i) {
                float aY = acc[t][i] + bt + E_proj[opr[i] * 128 + col];
                float y = aY / (1.0f + __expf(-aY));
                acc[t][i] = y;
                s[i] += y;
                sq[i] = fmaf(y, y, sq[i]);
            }
        }
        #pragma unroll
        for (int m = 1; m <= 8; m <<= 1) {
            #pragma unroll
            for (int i = 0; i < 4; ++i) {
                s[i] += __shfl_xor(s[i], m);
                sq[i] += __shfl_xor(sq[i], m);
            }
        }
        if (l15 == 0) {
            #pragma unroll
            for (int i = 0; i < 4; ++i) {
                int rr = wr * 16 + (lane >> 4) * 4 + i;
                pS[rr][wc] = s[i];
                pQ[rr][wc] = sq[i];
            }
        }
        __syncthreads();

        #pragma unroll
        for (int i = 0; i < 4; ++i) {
            int rr = wr * 16 + (lane >> 4) * 4 + i;
            float st = pS[rr][0] + pS[rr][1];
            float qt = pQ[rr][0] + pQ[rr][1];
            float mu = st * (1.0f / 128.0f);
            float var = qt * (1.0f / 128.0f) - mu * mu;
            float inv = rsqrtf(var + LN_EPS);
            if (node0 + (rr >> 1) < N) {
                u16* xr = x + ((size_t)node0 * 2 + rr) * 128;
                #pragma unroll
                for (int t = 0; t < 4; ++t) {
                    int col = wc * 64 + t * 16 + l15;
                    xr[col] = f2bf((acc[t][i] - mu) * inv * gain[col] + beta[col]);
                }
            }
        }
    }
}

// -- fused mp layer: 512 threads, 8 waves; optional fused pooling (last layer)
__global__ __launch_bounds__(512) void k_mp_mfma(
    const int* __restrict__ row_ptr, const int* __restrict__ col_sorted,
    const float* __restrict__ invdeg, const u16* __restrict__ xin,
    const u16* __restrict__ Wt, const float* __restrict__ bias,
    const float* __restrict__ gain, const float* __restrict__ beta,
    u16* __restrict__ xout, const int* __restrict__ grp,
    float* __restrict__ pooled, int fuse, int N, int B, int ntiles)
{
    __shared__ u16 A[64 * KP];
    __shared__ u16 Wl[128 * KP];
    __shared__ float pS[64][2], pQ[64][2];
    const int tid = threadIdx.x;
    const int lane = tid & 63, w = tid >> 6;
    const int l15 = lane & 15;
    const int kq = (lane >> 4) * 8;
    const int r = tid >> 3, sl = tid & 7;
    const int wr = w & 3, wc = w >> 2;

    for (int i = tid; i < 2048; i += 512) {
        uint4 v = ((const uint4*)Wt)[i];
        *(uint4*)&Wl[(i >> 4) * KP + (i & 15) * 8] = v;
    }

    for (int tile = blockIdx.x; tile < ntiles; tile += gridDim.x) {
        const int node0 = tile * 32;
        {
            int nl = r >> 1, b = r & 1;
            int node = min(node0 + nl, N - 1);
            int e0 = row_ptr[node], e1 = row_ptr[node + 1];
            float sc = invdeg[node];
            const u32* xb = (const u32*)xin + (size_t)b * 64 + sl * 8;
            float fa[16];
            #pragma unroll
            for (int j = 0; j < 16; ++j) fa[j] = 0.f;
            int e = e0;
            for (; e + 2 <= e1; e += 2) {
                int c0 = col_sorted[e], c1 = col_sorted[e + 1];
                const uint4* p0 = (const uint4*)(xb + (size_t)c0 * 128);
                const uint4* p1 = (const uint4*)(xb + (size_t)c1 * 128);
                uint4 u0 = p0[0], u1 = p0[1];
                uint4 w0 = p1[0], w1 = p1[1];
                acc_u4(fa, u0);     acc_u4(fa + 8, u1);
                acc_u4(fa, w0);     acc_u4(fa + 8, w1);
            }
            if (e < e1) {
                const uint4* p0 = (const uint4*)(xb + (size_t)col_sorted[e] * 128);
                uint4 u0 = p0[0], u1 = p0[1];
                acc_u4(fa, u0);     acc_u4(fa + 8, u1);
            }
            u32 pk[8];
            #pragma unroll
            for (int j = 0; j < 8; ++j)
                pk[j] = (u32)f2bf(fa[2 * j] * sc) | ((u32)f2bf(fa[2 * j + 1] * sc) << 16);
            uint4* dst = (uint4*)&A[r * KP + sl * 16];
            dst[0] = make_uint4(pk[0], pk[1], pk[2], pk[3]);
            dst[1] = make_uint4(pk[4], pk[5], pk[6], pk[7]);
        }
        __syncthreads();

        const int arow = wr * 16 + l15;
        bf16x8 a[4];
        #pragma unroll
        for (int kt = 0; kt < 4; ++kt)
            a[kt] = *(const bf16x8*)&A[arow * KP + kt * 32 + kq];
        f32x4 acc[4];
        #pragma unroll
        for (int t = 0; t < 4; ++t) {
            int bcol = wc * 64 + t * 16 + l15;
            f32x4 c4 = {0.f, 0.f, 0.f, 0.f};
            #pragma unroll
            for (int kt = 0; kt < 4; ++kt) {
                bf16x8 bfr = *(const bf16x8*)&Wl[bcol * KP + kt * 32 + kq];
                c4 = __builtin_amdgcn_mfma_f32_16x16x32_bf16(a[kt], bfr, c4, 0, 0, 0);
            }
            acc[t] = c4;
        }

        float s[4] = {0, 0, 0, 0}, sq[4] = {0, 0, 0, 0};
        #pragma unroll
        for (int t = 0; t < 4; ++t) {
            int col = wc * 64 + t * 16 + l15;
            float bt = bias[col];
            #pragma unroll
            for (int i = 0; i < 4; ++i) {
                float aY = acc[t][i] + bt;
                float y = aY / (1.0f + __expf(-aY));
                acc[t][i] = y;
                s[i] += y;
                sq[i] = fmaf(y, y, sq[i]);
            }
        }
        #pragma unroll
        for (int m = 1; m <= 8; m <<= 1) {
            #pragma unroll
            for (int i = 0; i < 4; ++i) {
                s[i] += __shfl_xor(s[i], m);
                sq[i] += __shfl_xor(sq[i], m);
            }
        }
        if (l15 == 0) {
            #pragma unroll
            for (int i = 0; i < 4; ++i) {
                int rr = wr * 16 + (lane >> 4) * 4 + i;
                pS[rr][wc] = s[i];
                pQ[rr][wc] = sq[i];
            }
        }
        __syncthreads();

        if (!fuse) {
            #pragma unroll
            for (int i = 0; i < 4; ++i) {
                int rr = wr * 16 + (lane >> 4) * 4 + i;
                float st = pS[rr][0] + pS[rr][1];
                float qt = pQ[rr][0] + pQ[rr][1];
                float mu = st * (1.0f / 128.0f);
                float var = qt * (1.0f / 128.0f) - mu * mu;
                float inv = rsqrtf(var + LN_EPS);
                if (node0 + (rr >> 1) < N) {
                    u16* xr = xout + ((size_t)node0 * 2 + rr) * 128;
                    #pragma unroll
                    for (int t = 0; t < 4; ++t) {
                        int col = wc * 64 + t * 16 + l15;
                        xr[col] = f2bf((acc[t][i] - mu) * inv * gain[col] + beta[col]);
                    }
                }
            }
        } else {
            // fused pooling: finish LN into y, accumulate per-(b,col) wave sums
            int nlo = node0 + wr * 8;
            int g_lo = grp[min(nlo, N - 1)];
            int g_hi = grp[min(nlo + 7, N - 1)];
            float gnr[4], btr2[4];
            #pragma unroll
            for (int t = 0; t < 4; ++t) {
                int col = wc * 64 + t * 16 + l15;
                gnr[t] = gain[col]; btr2[t] = beta[col];
            }
            if (g_lo == g_hi) {
                float sb0[4] = {0, 0, 0, 0}, sb1[4] = {0, 0, 0, 0};
                #pragma unroll
                for (int i = 0; i < 4; ++i) {
                    int rr = wr * 16 + (lane >> 4) * 4 + i;
                    int node = node0 + (rr >> 1);
                    float st = pS[rr][0] + pS[rr][1];
                    float qt = pQ[rr][0] + pQ[rr][1];
                    float mu = st * (1.0f / 128.0f);
                    float var = qt * (1.0f / 128.0f) - mu * mu;
                    float inv = rsqrtf(var + LN_EPS);
                    float msk = (node < N) ? 1.f : 0.f;
                    #pragma unroll
                    for (int t = 0; t < 4; ++t) {
                        float y = ((acc[t][i] - mu) * inv * gnr[t] + btr2[t]) * msk;
                        if (i & 1) sb1[t] += y; else sb0[t] += y;
                    }
                }
                #pragma unroll
                for (int t = 0; t < 4; ++t) {
                    sb0[t] += __shfl_xor(sb0[t], 16); sb1[t] += __shfl_xor(sb1[t], 16);
                    sb0[t] += __shfl_xor(sb0[t], 32); sb1[t] += __shfl_xor(sb1[t], 32);
                }
                if ((lane >> 4) == 0) {
                    #pragma unroll
                    for (int t = 0; t < 4; ++t) {
                        int col = wc * 64 + t * 16 + l15;
                        atomicAdd(&pooled[(g_lo * B + 0) * 128 + col], sb0[t]);
                        atomicAdd(&pooled[(g_lo * B + 1) * 128 + col], sb1[t]);
                    }
                }
            } else {
                // group boundary tile: per-row atomics (rare)
                #pragma unroll
                for (int i = 0; i < 4; ++i) {
                    int rr = wr * 16 + (lane >> 4) * 4 + i;
                    int node = node0 + (rr >> 1);
                    if (node < N) {
                        float st = pS[rr][0] + pS[rr][1];
                        float qt = pQ[rr][0] + pQ[rr][1];
                        float mu = st * (1.0f / 128.0f);
                        float var = qt * (1.0f / 128.0f) - mu * mu;
                        float inv = rsqrtf(var + LN_EPS);
                        int g = grp[node];
                        int b = rr & 1;
                        #pragma unroll
                        for (int t = 0; t < 4; ++t) {
                            int col = wc * 64 + t * 16 + l15;
                            float y = (acc[t][i] - mu) * inv * gnr[t] + btr2[t];
                            atomicAdd(&pooled[(g * B + b) * 128 + col], y);
                        }
                    }
                }
            }
        }
    }
}

__global__ __launch_bounds__(128) void k_proj(
    const float* __restrict__ pooled, const float* __restrict__ Wp,
    const float* __restrict__ bp, float* __restrict__ out, int GB)
{
    int gb = blockIdx.x;
    int tid = threadIdx.x;
    float v = pooled[gb * 128 + tid] * Wp[tid];
    v += __shfl_down(v, 32);
    v += __shfl_down(v, 16);
    v += __shfl_down(v, 8);
    v += __shfl_down(v, 4);
    v += __shfl_down(v, 2);
    v += __shfl_down(v, 1);
    __shared__ float red[2];
    if ((tid & 63) == 0) red[tid >> 6] = v;
    __syncthreads();
    if (tid == 0) out[gb] = red[0] + red[1] + bp[0];
}

// ---------------- host ----------------
extern "C" void kernel_launch(void* const* d_in, const int* in_sizes, int n_in,
                              void* d_out, int out_size, void* d_ws, size_t ws_size,
                              hipStream_t stream) {
    const float* features = (const float*)d_in[0];
    const int* edge_index = (const int*)d_in[1];
    const int* lengths    = (const int*)d_in[2];
    const float* emb      = (const float*)d_in[3];
    const float* W_in     = (const float*)d_in[4];
    const float* b_in     = (const float*)d_in[5];
    const float* g_in     = (const float*)d_in[6];
    const float* beta_in  = (const float*)d_in[7];
    const float* msg_W    = (const float*)d_in[8];
    const float* msg_b    = (const float*)d_in[9];
    const float* msg_g    = (const float*)d_in[10];
    const float* msg_beta = (const float*)d_in[11];
    const float* W_proj   = (const float*)d_in[12];
    const float* b_proj   = (const float*)d_in[13];
    float* out = (float*)d_out;

    const int E = in_sizes[1] / 2;
    const int G = in_sizes[2];
    const int B = out_size / G;
    const int C = in_sizes[5];           // 128
    const int F = 128;
    const int N = in_sizes[0] / (B * F);
    const int M = B * N;
    const int L = in_sizes[9] / C;       // 3

    const int* rows = edge_index;
    const int* cols = edge_index + E;

    // workspace carve-up (16B-aligned)
    u16* buf0   = (u16*)d_ws;                               // M*128 (interleaved [n][b][c])
    u16* buf1   = buf0 + (size_t)M * 128;                   // M*128
    u16* Wt_in  = buf1 + (size_t)M * 128;                   // 128*128
    u16* Wt_msg = Wt_in + 128 * 128;                        // 3*128*128
    float* E_proj = (float*)(Wt_msg + 3 * 128 * 128);       // 128*128 f32
    float* invdeg = E_proj + 128 * 128;                     // N
    int*   deg    = (int*)(invdeg + N);                     // N (reused as cursor)
    float* pooled = (float*)(deg + N);                      // G*B*128
    int*   row_ptr = (int*)(pooled + (size_t)G * B * 128);  // N+1
    int*   col_sorted = row_ptr + N + 1;                    // E
    int*   bsum   = col_sorted + E;                         // ~64
    int*   gstart = bsum + 64;                              // G+1
    int*   grp    = gstart + G + 1;                         // N

    const int nb_scan = (N + SCAN_ELEMS - 1) / SCAN_ELEMS;
    const int nt32 = (N + 31) / 32;
    const int grid_mp = nt32 < 1024 ? nt32 : 1024;

    // weight prep
    {
        int total = 4 * 128 * 128;
        k_wprep<<<(total + 255) / 256, 256, 0, stream>>>(W_in, msg_W, Wt_in, Wt_msg);
        k_eproj<<<128, 128, 0, stream>>>(W_in, emb, E_proj);
    }

    // degree + CSR + group map
    hipMemsetAsync(deg, 0, (size_t)N * sizeof(int), stream);
    hipMemsetAsync(pooled, 0, (size_t)G * B * 128 * sizeof(float), stream);
    k_deg<<<(E + 255) / 256, 256, 0, stream>>>(rows, deg, E);
    k_invdeg<<<(N + 255) / 256, 256, 0, stream>>>(deg, invdeg, N);
    k_scan1<<<nb_scan, SCAN_T, 0, stream>>>(deg, row_ptr, bsum, N);
    k_scan2<<<1, 1, 0, stream>>>(bsum, nb_scan, row_ptr, N);
    k_scan3<<<nb_scan, SCAN_T, 0, stream>>>(row_ptr, bsum, N);
    k_copy_cursor<<<(N + 255) / 256, 256, 0, stream>>>(row_ptr, deg, N);
    k_bucket<<<(E + 255) / 256, 256, 0, stream>>>(rows, cols, deg, col_sorted, E);
    k_gstart<<<1, 1, 0, stream>>>(lengths, gstart, G);
    k_grp<<<(N + 255) / 256, 256, 0, stream>>>(gstart, grp, N, G);

    // input layer -> buf0 (interleaved)
    k_input_mfma<<<grid_mp, 512, 0, stream>>>(features, E_proj, Wt_in,
                                              b_in, g_in, beta_in, buf0, N, nt32);

    // fused mp layers (ping-pong); last layer fuses pooling
    u16* bufs[2] = {buf0, buf1};
    int cur = 0;
    for (int l = 0; l < L; ++l) {
        int fuse = (l == L - 1) ? 1 : 0;
        k_mp_mfma<<<grid_mp, 512, 0, stream>>>(row_ptr, col_sorted, invdeg,
                                               bufs[cur], Wt_msg + (size_t)l * 128 * 128,
                                               msg_b + (size_t)l * C, msg_g + (size_t)l * C,
                                               msg_beta + (size_t)l * C,
                                               bufs[1 - cur], grp, pooled, fuse, N, B, nt32);
        cur = 1 - cur;
    }

    // projection
    k_proj<<<G * B, 128, 0, stream>>>(pooled, W_proj, b_proj, out, G * B);
}

// Round 18
// 330.052 us; speedup vs baseline: 1.3080x; 1.2540x over previous
//
#include <hip/hip_runtime.h>
#include <cstddef>

#define LN_EPS 1e-5f
typedef unsigned short u16;
typedef unsigned int u32;
typedef __attribute__((ext_vector_type(8))) short bf16x8;
typedef __attribute__((ext_vector_type(4))) float f32x4;

constexpr int SCAN_T = 256, SCAN_V = 8, SCAN_ELEMS = SCAN_T * SCAN_V;
constexpr int KP = 136;   // LDS stride (elems): 272B row stride

__device__ inline u16 f2bf(float f) {
    u32 u = __float_as_uint(f);
    u += 0x7FFFu + ((u >> 16) & 1u);
    return (u16)(u >> 16);
}
__device__ inline float bf2f(u16 h) { return __uint_as_float((u32)h << 16); }

__device__ inline void acc_u4(float* a, uint4 u) {
    a[0] += bf2f((u16)(u.x & 0xFFFF)); a[1] += bf2f((u16)(u.x >> 16));
    a[2] += bf2f((u16)(u.y & 0xFFFF)); a[3] += bf2f((u16)(u.y >> 16));
    a[4] += bf2f((u16)(u.z & 0xFFFF)); a[5] += bf2f((u16)(u.z >> 16));
    a[6] += bf2f((u16)(u.w & 0xFFFF)); a[7] += bf2f((u16)(u.w >> 16));
}

// ---------------- degree / inverse degree ----------------
__global__ __launch_bounds__(256) void k_deg(const int* __restrict__ rows,
                                             int* __restrict__ deg, int E) {
    int e = blockIdx.x * 256 + threadIdx.x;
    if (e < E) atomicAdd(&deg[rows[e]], 1);
}

__global__ __launch_bounds__(256) void k_invdeg(const int* __restrict__ deg,
                                                float* __restrict__ invdeg, int N) {
    int i = blockIdx.x * 256 + threadIdx.x;
    if (i < N) invdeg[i] = 1.0f / (float)max(deg[i], 1);
}

// ---------------- group map ----------------
__global__ void k_gstart(const int* __restrict__ lengths, int* __restrict__ gstart, int G) {
    int run = 0;
    for (int i = 0; i < G; ++i) { gstart[i] = run; run += lengths[i]; }
    gstart[G] = run;
}

__global__ __launch_bounds__(256) void k_grp(const int* __restrict__ gstart,
                                             int* __restrict__ grp, int N, int G) {
    int i = blockIdx.x * 256 + threadIdx.x;
    if (i < N) {
        int g = 0;
        while (g + 1 < G && i >= gstart[g + 1]) ++g;
        grp[i] = g;
    }
}

// ---------------- CSR build ----------------
__global__ __launch_bounds__(SCAN_T) void k_scan1(const int* __restrict__ deg,
                                                  int* __restrict__ row_ptr,
                                                  int* __restrict__ bsum, int N) {
    __shared__ int ts[SCAN_T];
    int t = threadIdx.x;
    int base = blockIdx.x * SCAN_ELEMS;
    int v[SCAN_V];
    int s = 0;
    #pragma unroll
    for (int j = 0; j < SCAN_V; ++j) {
        int i = base + t * SCAN_V + j;
        v[j] = (i < N) ? deg[i] : 0;
        s += v[j];
    }
    ts[t] = s;
    __syncthreads();
    for (int off = 1; off < SCAN_T; off <<= 1) {
        int val = (t >= off) ? ts[t - off] : 0;
        __syncthreads();
        ts[t] += val;
        __syncthreads();
    }
    int excl = (t > 0) ? ts[t - 1] : 0;
    #pragma unroll
    for (int j = 0; j < SCAN_V; ++j) {
        int i = base + t * SCAN_V + j;
        if (i < N) row_ptr[i] = excl;
        excl += v[j];
    }
    if (t == SCAN_T - 1) bsum[blockIdx.x] = ts[SCAN_T - 1];
}

__global__ void k_scan2(int* __restrict__ bsum, int nb, int* __restrict__ row_ptr, int N) {
    int run = 0;
    for (int i = 0; i < nb; ++i) {
        int v = bsum[i];
        bsum[i] = run;
        run += v;
    }
    row_ptr[N] = run;
}

__global__ __launch_bounds__(SCAN_T) void k_scan3(int* __restrict__ row_ptr,
                                                  const int* __restrict__ bsum, int N) {
    int add = bsum[blockIdx.x];
    int base = blockIdx.x * SCAN_ELEMS;
    #pragma unroll
    for (int j = 0; j < SCAN_V; ++j) {
        int i = base + threadIdx.x * SCAN_V + j;
        if (i < N) row_ptr[i] += add;
    }
}

__global__ __launch_bounds__(256) void k_copy_cursor(const int* __restrict__ row_ptr,
                                                     int* __restrict__ cursor, int N) {
    int i = blockIdx.x * 256 + threadIdx.x;
    if (i < N) cursor[i] = row_ptr[i];
}

__global__ __launch_bounds__(256) void k_bucket(const int* __restrict__ rows,
                                                const int* __restrict__ cols,
                                                int* __restrict__ cursor,
                                                int* __restrict__ col_sorted, int E) {
    int e = blockIdx.x * 256 + threadIdx.x;
    if (e < E) {
        int r = rows[e];
        int pos = atomicAdd(&cursor[r], 1);
        col_sorted[pos] = cols[e];
    }
}

// ---------------- weight prep ----------------
__global__ __launch_bounds__(256) void k_wprep(const float* __restrict__ W_in,
                                               const float* __restrict__ msg_W,
                                               u16* __restrict__ Wt_in,
                                               u16* __restrict__ Wt_msg) {
    int idx = blockIdx.x * 256 + threadIdx.x;
    const int t1 = 128 * 128;
    if (idx < t1) {
        int c = idx >> 7, k = idx & 127;
        float v = (k >= 1) ? W_in[(31 + k) * 128 + c] : 0.f;
        Wt_in[idx] = f2bf(v);
    } else {
        idx -= t1;
        if (idx < 3 * 128 * 128) {
            int l = idx / (128 * 128);
            int r = idx & (128 * 128 - 1);
            int c = r >> 7, k = r & 127;
            Wt_msg[idx] = f2bf(msg_W[l * 16384 + k * 128 + c]);
        }
    }
}

// E_proj[op][c] = sum_j emb[op][j] * W_in[j][c]
__global__ __launch_bounds__(128) void k_eproj(const float* __restrict__ W_in,
                                               const float* __restrict__ emb,
                                               float* __restrict__ E_proj) {
    __shared__ float es[32];
    int op = blockIdx.x, c = threadIdx.x;
    if (c < 32) es[c] = emb[op * 32 + c];
    __syncthreads();
    float s = 0.f;
    #pragma unroll
    for (int j = 0; j < 32; ++j) s = fmaf(es[j], W_in[j * 128 + c], s);
    E_proj[op * 128 + c] = s;
}

// -- input layer: 512 threads / 8 waves share 64-row tile + Wl ----------------
__global__ __launch_bounds__(512) void k_input_mfma(
    const float* __restrict__ features, const float* __restrict__ E_proj,
    const u16* __restrict__ Wt,
    const float* __restrict__ bias, const float* __restrict__ gain,
    const float* __restrict__ beta, u16* __restrict__ x, int N, int ntiles)
{
    __shared__ u16 A[64 * KP];
    __shared__ u16 Wl[128 * KP];
    __shared__ int ops[64];
    __shared__ float pS[64][2], pQ[64][2];
    const int tid = threadIdx.x;
    const int lane = tid & 63, w = tid >> 6;
    const int l15 = lane & 15;
    const int kq = (lane >> 4) * 8;
    const int r = tid >> 3, sl = tid & 7;
    const int wr = w & 3, wc = w >> 2;

    for (int i = tid; i < 2048; i += 512) {
        uint4 v = ((const uint4*)Wt)[i];
        *(uint4*)&Wl[(i >> 4) * KP + (i & 15) * 8] = v;
    }

    for (int tile = blockIdx.x; tile < ntiles; tile += gridDim.x) {
        const int node0 = tile * 32;
        {
            int nl = r >> 1, b = r & 1;
            int node = min(node0 + nl, N - 1);
            const float* fr = features + ((size_t)b * N + node) * 128 + sl * 16;
            float4 v0 = ((const float4*)fr)[0];
            float4 v1 = ((const float4*)fr)[1];
            float4 v2 = ((const float4*)fr)[2];
            float4 v3 = ((const float4*)fr)[3];
            if (sl == 0) {
                int op = (int)v0.x;
                op = op < 0 ? 0 : (op > 127 ? 127 : op);
                ops[r] = op;
            }
            u32 pk[8];
            pk[0] = (u32)f2bf(v0.x) | ((u32)f2bf(v0.y) << 16);
            pk[1] = (u32)f2bf(v0.z) | ((u32)f2bf(v0.w) << 16);
            pk[2] = (u32)f2bf(v1.x) | ((u32)f2bf(v1.y) << 16);
            pk[3] = (u32)f2bf(v1.z) | ((u32)f2bf(v1.w) << 16);
            pk[4] = (u32)f2bf(v2.x) | ((u32)f2bf(v2.y) << 16);
            pk[5] = (u32)f2bf(v2.z) | ((u32)f2bf(v2.w) << 16);
            pk[6] = (u32)f2bf(v3.x) | ((u32)f2bf(v3.y) << 16);
            pk[7] = (u32)f2bf(v3.z) | ((u32)f2bf(v3.w) << 16);
            uint4* dst = (uint4*)&A[r * KP + sl * 16];
            dst[0] = make_uint4(pk[0], pk[1], pk[2], pk[3]);
            dst[1] = make_uint4(pk[4], pk[5], pk[6], pk[7]);
        }
        __syncthreads();

        const int arow = wr * 16 + l15;
        bf16x8 a[4];
        #pragma unroll
        for (int kt = 0; kt < 4; ++kt)
            a[kt] = *(const bf16x8*)&A[arow * KP + kt * 32 + kq];
        f32x4 acc[4];
        #pragma unroll
        for (int t = 0; t < 4; ++t) {
            int bcol = wc * 64 + t * 16 + l15;
            f32x4 c4 = {0.f, 0.f, 0.f, 0.f};
            #pragma unroll
            for (int kt = 0; kt < 4; ++kt) {
                bf16x8 b = *(const bf16x8*)&Wl[bcol * KP + kt * 32 + kq];
                c4 = __builtin_amdgcn_mfma_f32_16x16x32_bf16(a[kt], b, c4, 0, 0, 0);
            }
            acc[t] = c4;
        }

        int opr[4];
        #pragma unroll
        for (int i = 0; i < 4; ++i) opr[i] = ops[wr * 16 + (lane >> 4) * 4 + i];

        float s[4] = {0, 0, 0, 0}, sq[4] = {0, 0, 0, 0};
        #pragma unroll
        for (int t = 0; t < 4; ++t) {
            int col = wc * 64 + t * 16 + l15;
            float bt = bias[col];
            #pragma unroll
            for (int i = 0; i < 4; ++i) {
                float aY = acc[t][i] + bt + E_proj[opr[i] * 128 + col];
                float y = aY / (1.0f + __expf(-aY));
                acc[t][i] = y;
                s[i] += y;
                sq[i] = fmaf(y, y, sq[i]);
            }
        }
        #pragma unroll
        for (int m = 1; m <= 8; m <<= 1) {
            #pragma unroll
            for (int i = 0; i < 4; ++i) {
                s[i] += __shfl_xor(s[i], m);
                sq[i] += __shfl_xor(sq[i], m);
            }
        }
        if (l15 == 0) {
            #pragma unroll
            for (int i = 0; i < 4; ++i) {
                int rr = wr * 16 + (lane >> 4) * 4 + i;
                pS[rr][wc] = s[i];
                pQ[rr][wc] = sq[i];
            }
        }
        __syncthreads();

        #pragma unroll
        for (int i = 0; i < 4; ++i) {
            int rr = wr * 16 + (lane >> 4) * 4 + i;
            float st = pS[rr][0] + pS[rr][1];
            float qt = pQ[rr][0] + pQ[rr][1];
            float mu = st * (1.0f / 128.0f);
            float var = qt * (1.0f / 128.0f) - mu * mu;
            float inv = rsqrtf(var + LN_EPS);
            if (node0 + (rr >> 1) < N) {
                u16* xr = x + ((size_t)node0 * 2 + rr) * 128;
                #pragma unroll
                for (int t = 0; t < 4; ++t) {
                    int col = wc * 64 + t * 16 + l15;
                    xr[col] = f2bf((acc[t][i] - mu) * inv * gain[col] + beta[col]);
                }
            }
        }
    }
}

// -- fused mp layer: 512 threads, 8 waves; optional fused pooling (last layer)
// fused path: per-wave partial pool sums -> plain stores to wavesum scratch;
// boundary tiles (group change inside tile) use rare per-row atomics + zeros.
__global__ __launch_bounds__(512) void k_mp_mfma(
    const int* __restrict__ row_ptr, const int* __restrict__ col_sorted,
    const float* __restrict__ invdeg, const u16* __restrict__ xin,
    const u16* __restrict__ Wt, const float* __restrict__ bias,
    const float* __restrict__ gain, const float* __restrict__ beta,
    u16* __restrict__ xout, const int* __restrict__ grp,
    float* __restrict__ pooled, float* __restrict__ wavesum,
    int fuse, int N, int B, int ntiles)
{
    __shared__ u16 A[64 * KP];
    __shared__ u16 Wl[128 * KP];
    __shared__ float pS[64][2], pQ[64][2];
    const int tid = threadIdx.x;
    const int lane = tid & 63, w = tid >> 6;
    const int l15 = lane & 15;
    const int kq = (lane >> 4) * 8;
    const int r = tid >> 3, sl = tid & 7;
    const int wr = w & 3, wc = w >> 2;

    for (int i = tid; i < 2048; i += 512) {
        uint4 v = ((const uint4*)Wt)[i];
        *(uint4*)&Wl[(i >> 4) * KP + (i & 15) * 8] = v;
    }

    for (int tile = blockIdx.x; tile < ntiles; tile += gridDim.x) {
        const int node0 = tile * 32;
        {
            int nl = r >> 1, b = r & 1;
            int node = min(node0 + nl, N - 1);
            int e0 = row_ptr[node], e1 = row_ptr[node + 1];
            float sc = invdeg[node];
            const u32* xb = (const u32*)xin + (size_t)b * 64 + sl * 8;
            float fa[16];
            #pragma unroll
            for (int j = 0; j < 16; ++j) fa[j] = 0.f;
            int e = e0;
            for (; e + 2 <= e1; e += 2) {
                int c0 = col_sorted[e], c1 = col_sorted[e + 1];
                const uint4* p0 = (const uint4*)(xb + (size_t)c0 * 128);
                const uint4* p1 = (const uint4*)(xb + (size_t)c1 * 128);
                uint4 u0 = p0[0], u1 = p0[1];
                uint4 w0 = p1[0], w1 = p1[1];
                acc_u4(fa, u0);     acc_u4(fa + 8, u1);
                acc_u4(fa, w0);     acc_u4(fa + 8, w1);
            }
            if (e < e1) {
                const uint4* p0 = (const uint4*)(xb + (size_t)col_sorted[e] * 128);
                uint4 u0 = p0[0], u1 = p0[1];
                acc_u4(fa, u0);     acc_u4(fa + 8, u1);
            }
            u32 pk[8];
            #pragma unroll
            for (int j = 0; j < 8; ++j)
                pk[j] = (u32)f2bf(fa[2 * j] * sc) | ((u32)f2bf(fa[2 * j + 1] * sc) << 16);
            uint4* dst = (uint4*)&A[r * KP + sl * 16];
            dst[0] = make_uint4(pk[0], pk[1], pk[2], pk[3]);
            dst[1] = make_uint4(pk[4], pk[5], pk[6], pk[7]);
        }
        __syncthreads();

        const int arow = wr * 16 + l15;
        bf16x8 a[4];
        #pragma unroll
        for (int kt = 0; kt < 4; ++kt)
            a[kt] = *(const bf16x8*)&A[arow * KP + kt * 32 + kq];
        f32x4 acc[4];
        #pragma unroll
        for (int t = 0; t < 4; ++t) {
            int bcol = wc * 64 + t * 16 + l15;
            f32x4 c4 = {0.f, 0.f, 0.f, 0.f};
            #pragma unroll
            for (int kt = 0; kt < 4; ++kt) {
                bf16x8 bfr = *(const bf16x8*)&Wl[bcol * KP + kt * 32 + kq];
                c4 = __builtin_amdgcn_mfma_f32_16x16x32_bf16(a[kt], bfr, c4, 0, 0, 0);
            }
            acc[t] = c4;
        }

        float s[4] = {0, 0, 0, 0}, sq[4] = {0, 0, 0, 0};
        #pragma unroll
        for (int t = 0; t < 4; ++t) {
            int col = wc * 64 + t * 16 + l15;
            float bt = bias[col];
            #pragma unroll
            for (int i = 0; i < 4; ++i) {
                float aY = acc[t][i] + bt;
                float y = aY / (1.0f + __expf(-aY));
                acc[t][i] = y;
                s[i] += y;
                sq[i] = fmaf(y, y, sq[i]);
            }
        }
        #pragma unroll
        for (int m = 1; m <= 8; m <<= 1) {
            #pragma unroll
            for (int i = 0; i < 4; ++i) {
                s[i] += __shfl_xor(s[i], m);
                sq[i] += __shfl_xor(sq[i], m);
            }
        }
        if (l15 == 0) {
            #pragma unroll
            for (int i = 0; i < 4; ++i) {
                int rr = wr * 16 + (lane >> 4) * 4 + i;
                pS[rr][wc] = s[i];
                pQ[rr][wc] = sq[i];
            }
        }
        __syncthreads();

        if (!fuse) {
            #pragma unroll
            for (int i = 0; i < 4; ++i) {
                int rr = wr * 16 + (lane >> 4) * 4 + i;
                float st = pS[rr][0] + pS[rr][1];
                float qt = pQ[rr][0] + pQ[rr][1];
                float mu = st * (1.0f / 128.0f);
                float var = qt * (1.0f / 128.0f) - mu * mu;
                float inv = rsqrtf(var + LN_EPS);
                if (node0 + (rr >> 1) < N) {
                    u16* xr = xout + ((size_t)node0 * 2 + rr) * 128;
                    #pragma unroll
                    for (int t = 0; t < 4; ++t) {
                        int col = wc * 64 + t * 16 + l15;
                        xr[col] = f2bf((acc[t][i] - mu) * inv * gain[col] + beta[col]);
                    }
                }
            }
        } else {
            int gt0 = grp[node0];
            int gt1 = grp[min(node0 + 31, N - 1)];
            float gnr[4], btr2[4];
            #pragma unroll
            for (int t = 0; t < 4; ++t) {
                int col = wc * 64 + t * 16 + l15;
                gnr[t] = gain[col]; btr2[t] = beta[col];
            }
            float sb0[4] = {0, 0, 0, 0}, sb1[4] = {0, 0, 0, 0};
            if (gt0 == gt1) {
                #pragma unroll
                for (int i = 0; i < 4; ++i) {
                    int rr = wr * 16 + (lane >> 4) * 4 + i;
                    int node = node0 + (rr >> 1);
                    float st = pS[rr][0] + pS[rr][1];
                    float qt = pQ[rr][0] + pQ[rr][1];
                    float mu = st * (1.0f / 128.0f);
                    float var = qt * (1.0f / 128.0f) - mu * mu;
                    float inv = rsqrtf(var + LN_EPS);
                    float msk = (node < N) ? 1.f : 0.f;
                    #pragma unroll
                    for (int t = 0; t < 4; ++t) {
                        float y = ((acc[t][i] - mu) * inv * gnr[t] + btr2[t]) * msk;
                        if (i & 1) sb1[t] += y; else sb0[t] += y;
                    }
                }
                #pragma unroll
                for (int t = 0; t < 4; ++t) {
                    sb0[t] += __shfl_xor(sb0[t], 16); sb1[t] += __shfl_xor(sb1[t], 16);
                    sb0[t] += __shfl_xor(sb0[t], 32); sb1[t] += __shfl_xor(sb1[t], 32);
                }
            } else {
                // boundary tile: rare per-row atomics; wavesum gets zeros
                #pragma unroll
                for (int i = 0; i < 4; ++i) {
                    int rr = wr * 16 + (lane >> 4) * 4 + i;
                    int node = node0 + (rr >> 1);
                    if (node < N) {
                        float st = pS[rr][0] + pS[rr][1];
                        float qt = pQ[rr][0] + pQ[rr][1];
                        float mu = st * (1.0f / 128.0f);
                        float var = qt * (1.0f / 128.0f) - mu * mu;
                        float inv = rsqrtf(var + LN_EPS);
                        int g = grp[node];
                        int b = rr & 1;
                        #pragma unroll
                        for (int t = 0; t < 4; ++t) {
                            int col = wc * 64 + t * 16 + l15;
                            float y = (acc[t][i] - mu) * inv * gnr[t] + btr2[t];
                            atomicAdd(&pooled[(g * B + b) * 128 + col], y);
                        }
                    }
                }
            }
            // plain stores: wavesum[((tile*4 + wr)*2 + b)*128 + col]
            if ((lane >> 4) == 0) {
                float* w0p = wavesum + (((size_t)tile * 4 + wr) * 2 + 0) * 128;
                float* w1p = wavesum + (((size_t)tile * 4 + wr) * 2 + 1) * 128;
                #pragma unroll
                for (int t = 0; t < 4; ++t) {
                    int col = wc * 64 + t * 16 + l15;
                    w0p[col] = sb0[t];
                    w1p[col] = sb1[t];
                }
            }
        }
    }
}

// ---------------- pool reduce: wavesum -> pooled ----------------
__global__ __launch_bounds__(128) void k_pred(
    const float* __restrict__ wavesum, const int* __restrict__ gstart,
    float* __restrict__ pooled, int B, int G, int SPLIT, int ntiles)
{
    int blk = blockIdx.x;
    int split = blk % SPLIT;
    int gb = blk / SPLIT;
    int b = gb % B, g = gb / B;
    int col = threadIdx.x;
    int t0 = gstart[g] >> 5;
    int t1 = (gstart[g + 1] + 31) >> 5;
    if (t1 > ntiles) t1 = ntiles;
    int len = t1 - t0;
    int chunk = (len + SPLIT - 1) / SPLIT;
    int a0 = t0 + split * chunk;
    int a1 = min(t1, a0 + chunk);
    float s = 0.f;
    for (int t = a0; t < a1; ++t) {
        const float* wp = wavesum + ((size_t)t * 8 + b) * 128 + col;
        s += wp[0] + wp[256] + wp[512] + wp[768];
    }
    if (a1 > a0) atomicAdd(&pooled[(g * B + b) * 128 + col], s);
}

__global__ __launch_bounds__(128) void k_proj(
    const float* __restrict__ pooled, const float* __restrict__ Wp,
    const float* __restrict__ bp, float* __restrict__ out, int GB)
{
    int gb = blockIdx.x;
    int tid = threadIdx.x;
    float v = pooled[gb * 128 + tid] * Wp[tid];
    v += __shfl_down(v, 32);
    v += __shfl_down(v, 16);
    v += __shfl_down(v, 8);
    v += __shfl_down(v, 4);
    v += __shfl_down(v, 2);
    v += __shfl_down(v, 1);
    __shared__ float red[2];
    if ((tid & 63) == 0) red[tid >> 6] = v;
    __syncthreads();
    if (tid == 0) out[gb] = red[0] + red[1] + bp[0];
}

// ---------------- host ----------------
extern "C" void kernel_launch(void* const* d_in, const int* in_sizes, int n_in,
                              void* d_out, int out_size, void* d_ws, size_t ws_size,
                              hipStream_t stream) {
    const float* features = (const float*)d_in[0];
    const int* edge_index = (const int*)d_in[1];
    const int* lengths    = (const int*)d_in[2];
    const float* emb      = (const float*)d_in[3];
    const float* W_in     = (const float*)d_in[4];
    const float* b_in     = (const float*)d_in[5];
    const float* g_in     = (const float*)d_in[6];
    const float* beta_in  = (const float*)d_in[7];
    const float* msg_W    = (const float*)d_in[8];
    const float* msg_b    = (const float*)d_in[9];
    const float* msg_g    = (const float*)d_in[10];
    const float* msg_beta = (const float*)d_in[11];
    const float* W_proj   = (const float*)d_in[12];
    const float* b_proj   = (const float*)d_in[13];
    float* out = (float*)d_out;

    const int E = in_sizes[1] / 2;
    const int G = in_sizes[2];
    const int B = out_size / G;
    const int C = in_sizes[5];           // 128
    const int F = 128;
    const int N = in_sizes[0] / (B * F);
    const int M = B * N;
    const int L = in_sizes[9] / C;       // 3

    const int* rows = edge_index;
    const int* cols = edge_index + E;

    // workspace carve-up (16B-aligned)
    u16* buf0   = (u16*)d_ws;                               // M*128 (interleaved [n][b][c])
    u16* buf1   = buf0 + (size_t)M * 128;                   // M*128
    u16* Wt_in  = buf1 + (size_t)M * 128;                   // 128*128
    u16* Wt_msg = Wt_in + 128 * 128;                        // 3*128*128
    float* E_proj = (float*)(Wt_msg + 3 * 128 * 128);       // 128*128 f32
    float* invdeg = E_proj + 128 * 128;                     // N
    int*   deg    = (int*)(invdeg + N);                     // N (reused as cursor)
    float* pooled = (float*)(deg + N);                      // G*B*128
    int*   row_ptr = (int*)(pooled + (size_t)G * B * 128);  // N+1
    int*   col_sorted = row_ptr + N + 1;                    // E
    int*   bsum   = col_sorted + E;                         // ~64
    int*   gstart = bsum + 64;                              // G+1
    int*   grp    = gstart + G + 1;                         // N
    float* wavesum = (float*)(grp + N);                     // ntiles*8*128

    const int nb_scan = (N + SCAN_ELEMS - 1) / SCAN_ELEMS;
    const int nt32 = (N + 31) / 32;
    const int grid_mp = nt32 < 1024 ? nt32 : 1024;

    // weight prep
    {
        int total = 4 * 128 * 128;
        k_wprep<<<(total + 255) / 256, 256, 0, stream>>>(W_in, msg_W, Wt_in, Wt_msg);
        k_eproj<<<128, 128, 0, stream>>>(W_in, emb, E_proj);
    }

    // degree + CSR + group map
    hipMemsetAsync(deg, 0, (size_t)N * sizeof(int), stream);
    hipMemsetAsync(pooled, 0, (size_t)G * B * 128 * sizeof(float), stream);
    k_deg<<<(E + 255) / 256, 256, 0, stream>>>(rows, deg, E);
    k_invdeg<<<(N + 255) / 256, 256, 0, stream>>>(deg, invdeg, N);
    k_scan1<<<nb_scan, SCAN_T, 0, stream>>>(deg, row_ptr, bsum, N);
    k_scan2<<<1, 1, 0, stream>>>(bsum, nb_scan, row_ptr, N);
    k_scan3<<<nb_scan, SCAN_T, 0, stream>>>(row_ptr, bsum, N);
    k_copy_cursor<<<(N + 255) / 256, 256, 0, stream>>>(row_ptr, deg, N);
    k_bucket<<<(E + 255) / 256, 256, 0, stream>>>(rows, cols, deg, col_sorted, E);
    k_gstart<<<1, 1, 0, stream>>>(lengths, gstart, G);
    k_grp<<<(N + 255) / 256, 256, 0, stream>>>(gstart, grp, N, G);

    // input layer -> buf0 (interleaved)
    k_input_mfma<<<grid_mp, 512, 0, stream>>>(features, E_proj, Wt_in,
                                              b_in, g_in, beta_in, buf0, N, nt32);

    // fused mp layers (ping-pong); last layer fuses pooling via wavesum scratch
    u16* bufs[2] = {buf0, buf1};
    int cur = 0;
    for (int l = 0; l < L; ++l) {
        int fuse = (l == L - 1) ? 1 : 0;
        k_mp_mfma<<<grid_mp, 512, 0, stream>>>(row_ptr, col_sorted, invdeg,
                                               bufs[cur], Wt_msg + (size_t)l * 128 * 128,
                                               msg_b + (size_t)l * C, msg_g + (size_t)l * C,
                                               msg_beta + (size_t)l * C,
                                               bufs[1 - cur], grp, pooled, wavesum,
                                               fuse, N, B, nt32);
        cur = 1 - cur;
    }

    // pool reduce + projection
    const int SPLIT = 32;
    k_pred<<<G * B * SPLIT, 128, 0, stream>>>(wavesum, gstart, pooled, B, G, SPLIT, nt32);
    k_proj<<<G * B, 128, 0, stream>>>(pooled, W_proj, b_proj, out, G * B);
}

// Round 20
// 315.259 us; speedup vs baseline: 1.3693x; 1.0469x over previous
//
#include <hip/hip_runtime.h>
#include <cstddef>

#define LN_EPS 1e-5f
typedef unsigned short u16;
typedef unsigned int u32;
typedef __attribute__((ext_vector_type(2))) _Float16 h2;
typedef __attribute__((ext_vector_type(2))) __fp16 fp16x2;
typedef __attribute__((ext_vector_type(8))) _Float16 half8;
typedef __attribute__((ext_vector_type(4))) float f32x4;

constexpr int SCAN_T = 256, SCAN_V = 8, SCAN_ELEMS = SCAN_T * SCAN_V;
constexpr int KP = 136;   // LDS stride (elems): 272B row stride

__device__ inline u32 pkh2(float a, float b) {
    union { fp16x2 h; u32 u; } c;
    c.h = __builtin_amdgcn_cvt_pkrtz(a, b);
    return c.u;
}
__device__ inline u16 f2h(float f) {
    union { _Float16 h; u16 u; } c; c.h = (_Float16)f; return c.u;
}

// ---------------- degree / inverse degree ----------------
__global__ __launch_bounds__(256) void k_deg(const int* __restrict__ rows,
                                             int* __restrict__ deg, int E) {
    int e = blockIdx.x * 256 + threadIdx.x;
    if (e < E) atomicAdd(&deg[rows[e]], 1);
}

__global__ __launch_bounds__(256) void k_invdeg(const int* __restrict__ deg,
                                                float* __restrict__ invdeg, int N) {
    int i = blockIdx.x * 256 + threadIdx.x;
    if (i < N) invdeg[i] = 1.0f / (float)max(deg[i], 1);
}

// ---------------- group map ----------------
__global__ void k_gstart(const int* __restrict__ lengths, int* __restrict__ gstart, int G) {
    int run = 0;
    for (int i = 0; i < G; ++i) { gstart[i] = run; run += lengths[i]; }
    gstart[G] = run;
}

__global__ __launch_bounds__(256) void k_grp(const int* __restrict__ gstart,
                                             int* __restrict__ grp, int N, int G) {
    int i = blockIdx.x * 256 + threadIdx.x;
    if (i < N) {
        int g = 0;
        while (g + 1 < G && i >= gstart[g + 1]) ++g;
        grp[i] = g;
    }
}

// ---------------- CSR build ----------------
__global__ __launch_bounds__(SCAN_T) void k_scan1(const int* __restrict__ deg,
                                                  int* __restrict__ row_ptr,
                                                  int* __restrict__ bsum, int N) {
    __shared__ int ts[SCAN_T];
    int t = threadIdx.x;
    int base = blockIdx.x * SCAN_ELEMS;
    int v[SCAN_V];
    int s = 0;
    #pragma unroll
    for (int j = 0; j < SCAN_V; ++j) {
        int i = base + t * SCAN_V + j;
        v[j] = (i < N) ? deg[i] : 0;
        s += v[j];
    }
    ts[t] = s;
    __syncthreads();
    for (int off = 1; off < SCAN_T; off <<= 1) {
        int val = (t >= off) ? ts[t - off] : 0;
        __syncthreads();
        ts[t] += val;
        __syncthreads();
    }
    int excl = (t > 0) ? ts[t - 1] : 0;
    #pragma unroll
    for (int j = 0; j < SCAN_V; ++j) {
        int i = base + t * SCAN_V + j;
        if (i < N) row_ptr[i] = excl;
        excl += v[j];
    }
    if (t == SCAN_T - 1) bsum[blockIdx.x] = ts[SCAN_T - 1];
}

__global__ void k_scan2(int* __restrict__ bsum, int nb, int* __restrict__ row_ptr, int N) {
    int run = 0;
    for (int i = 0; i < nb; ++i) {
        int v = bsum[i];
        bsum[i] = run;
        run += v;
    }
    row_ptr[N] = run;
}

__global__ __launch_bounds__(SCAN_T) void k_scan3(int* __restrict__ row_ptr,
                                                  const int* __restrict__ bsum, int N) {
    int add = bsum[blockIdx.x];
    int base = blockIdx.x * SCAN_ELEMS;
    #pragma unroll
    for (int j = 0; j < SCAN_V; ++j) {
        int i = base + threadIdx.x * SCAN_V + j;
        if (i < N) row_ptr[i] += add;
    }
}

__global__ __launch_bounds__(256) void k_copy_cursor(const int* __restrict__ row_ptr,
                                                     int* __restrict__ cursor, int N) {
    int i = blockIdx.x * 256 + threadIdx.x;
    if (i < N) cursor[i] = row_ptr[i];
}

__global__ __launch_bounds__(256) void k_bucket(const int* __restrict__ rows,
                                                const int* __restrict__ cols,
                                                int* __restrict__ cursor,
                                                int* __restrict__ col_sorted, int E) {
    int e = blockIdx.x * 256 + threadIdx.x;
    if (e < E) {
        int r = rows[e];
        int pos = atomicAdd(&cursor[r], 1);
        col_sorted[pos] = cols[e];
    }
}

// ---------------- weight prep (fp16) ----------------
__global__ __launch_bounds__(256) void k_wprep(const float* __restrict__ W_in,
                                               const float* __restrict__ msg_W,
                                               u16* __restrict__ Wt_in,
                                               u16* __restrict__ Wt_msg) {
    int idx = blockIdx.x * 256 + threadIdx.x;
    const int t1 = 128 * 128;
    if (idx < t1) {
        int c = idx >> 7, k = idx & 127;
        float v = (k >= 1) ? W_in[(31 + k) * 128 + c] : 0.f;
        Wt_in[idx] = f2h(v);
    } else {
        idx -= t1;
        if (idx < 3 * 128 * 128) {
            int l = idx / (128 * 128);
            int r = idx & (128 * 128 - 1);
            int c = r >> 7, k = r & 127;
            Wt_msg[idx] = f2h(msg_W[l * 16384 + k * 128 + c]);
        }
    }
}

// E_proj[op][c] = sum_j emb[op][j] * W_in[j][c]
__global__ __launch_bounds__(128) void k_eproj(const float* __restrict__ W_in,
                                               const float* __restrict__ emb,
                                               float* __restrict__ E_proj) {
    __shared__ float es[32];
    int op = blockIdx.x, c = threadIdx.x;
    if (c < 32) es[c] = emb[op * 32 + c];
    __syncthreads();
    float s = 0.f;
    #pragma unroll
    for (int j = 0; j < 32; ++j) s = fmaf(es[j], W_in[j * 128 + c], s);
    E_proj[op * 128 + c] = s;
}

// -- input layer: 512 threads / 8 waves share 64-row tile + Wl (fp16) ---------
__global__ __launch_bounds__(512) void k_input_mfma(
    const float* __restrict__ features, const float* __restrict__ E_proj,
    const u16* __restrict__ Wt,
    const float* __restrict__ bias, const float* __restrict__ gain,
    const float* __restrict__ beta, u16* __restrict__ x, int N, int ntiles)
{
    __shared__ u16 A[64 * KP];
    __shared__ u16 Wl[128 * KP];
    __shared__ int ops[64];
    __shared__ float pS[64][2], pQ[64][2];
    const int tid = threadIdx.x;
    const int lane = tid & 63, w = tid >> 6;
    const int l15 = lane & 15;
    const int kq = (lane >> 4) * 8;
    const int r = tid >> 3, sl = tid & 7;
    const int wr = w & 3, wc = w >> 2;

    for (int i = tid; i < 2048; i += 512) {
        uint4 v = ((const uint4*)Wt)[i];
        *(uint4*)&Wl[(i >> 4) * KP + (i & 15) * 8] = v;
    }

    for (int tile = blockIdx.x; tile < ntiles; tile += gridDim.x) {
        const int node0 = tile * 32;
        {
            int nl = r >> 1, b = r & 1;
            int node = min(node0 + nl, N - 1);
            const float* fr = features + ((size_t)b * N + node) * 128 + sl * 16;
            float4 v0 = ((const float4*)fr)[0];
            float4 v1 = ((const float4*)fr)[1];
            float4 v2 = ((const float4*)fr)[2];
            float4 v3 = ((const float4*)fr)[3];
            if (sl == 0) {
                int op = (int)v0.x;
                op = op < 0 ? 0 : (op > 127 ? 127 : op);
                ops[r] = op;
            }
            u32 pk[8];
            pk[0] = pkh2(v0.x, v0.y);
            pk[1] = pkh2(v0.z, v0.w);
            pk[2] = pkh2(v1.x, v1.y);
            pk[3] = pkh2(v1.z, v1.w);
            pk[4] = pkh2(v2.x, v2.y);
            pk[5] = pkh2(v2.z, v2.w);
            pk[6] = pkh2(v3.x, v3.y);
            pk[7] = pkh2(v3.z, v3.w);
            uint4* dst = (uint4*)&A[r * KP + sl * 16];
            dst[0] = make_uint4(pk[0], pk[1], pk[2], pk[3]);
            dst[1] = make_uint4(pk[4], pk[5], pk[6], pk[7]);
        }
        __syncthreads();

        const int arow = wr * 16 + l15;
        half8 a[4];
        #pragma unroll
        for (int kt = 0; kt < 4; ++kt)
            a[kt] = *(const half8*)&A[arow * KP + kt * 32 + kq];
        f32x4 acc[4];
        #pragma unroll
        for (int t = 0; t < 4; ++t) {
            int bcol = wc * 64 + t * 16 + l15;
            f32x4 c4 = {0.f, 0.f, 0.f, 0.f};
            #pragma unroll
            for (int kt = 0; kt < 4; ++kt) {
                half8 b = *(const half8*)&Wl[bcol * KP + kt * 32 + kq];
                c4 = __builtin_amdgcn_mfma_f32_16x16x32_f16(a[kt], b, c4, 0, 0, 0);
            }
            acc[t] = c4;
        }

        int opr[4];
        #pragma unroll
        for (int i = 0; i < 4; ++i) opr[i] = ops[wr * 16 + (lane >> 4) * 4 + i];

        float s[4] = {0, 0, 0, 0}, sq[4] = {0, 0, 0, 0};
        #pragma unroll
        for (int t = 0; t < 4; ++t) {
            int col = wc * 64 + t * 16 + l15;
            float bt = bias[col];
            #pragma unroll
            for (int i = 0; i < 4; ++i) {
                float aY = acc[t][i] + bt + E_proj[opr[i] * 128 + col];
                float y = aY / (1.0f + __expf(-aY));
                acc[t][i] = y;
                s[i] += y;
                sq[i] = fmaf(y, y, sq[i]);
            }
        }
        #pragma unroll
        for (int m = 1; m <= 8; m <<= 1) {
            #pragma unroll
            for (int i = 0; i < 4; ++i) {
                s[i] += __shfl_xor(s[i], m);
                sq[i] += __shfl_xor(sq[i], m);
            }
        }
        if (l15 == 0) {
            #pragma unroll
            for (int i = 0; i < 4; ++i) {
                int rr = wr * 16 + (lane >> 4) * 4 + i;
                pS[rr][wc] = s[i];
                pQ[rr][wc] = sq[i];
            }
        }
        __syncthreads();

        #pragma unroll
        for (int i = 0; i < 4; ++i) {
            int rr = wr * 16 + (lane >> 4) * 4 + i;
            float st = pS[rr][0] + pS[rr][1];
            float qt = pQ[rr][0] + pQ[rr][1];
            float mu = st * (1.0f / 128.0f);
            float var = qt * (1.0f / 128.0f) - mu * mu;
            float inv = rsqrtf(var + LN_EPS);
            if (node0 + (rr >> 1) < N) {
                u16* xr = x + ((size_t)node0 * 2 + rr) * 128;
                #pragma unroll
                for (int t = 0; t < 4; ++t) {
                    int col = wc * 64 + t * 16 + l15;
                    xr[col] = f2h((acc[t][i] - mu) * inv * gain[col] + beta[col]);
                }
            }
        }
    }
}

// -- fused mp layer (fp16): packed-f16 gather; optional fused pooling ---------
__global__ __launch_bounds__(512) void k_mp_mfma(
    const int* __restrict__ row_ptr, const int* __restrict__ col_sorted,
    const float* __restrict__ invdeg, const u16* __restrict__ xin,
    const u16* __restrict__ Wt, const float* __restrict__ bias,
    const float* __restrict__ gain, const float* __restrict__ beta,
    u16* __restrict__ xout, const int* __restrict__ grp,
    float* __restrict__ pooled, float* __restrict__ wavesum,
    int fuse, int N, int B, int ntiles)
{
    __shared__ u16 A[64 * KP];
    __shared__ u16 Wl[128 * KP];
    __shared__ float pS[64][2], pQ[64][2];
    const int tid = threadIdx.x;
    const int lane = tid & 63, w = tid >> 6;
    const int l15 = lane & 15;
    const int kq = (lane >> 4) * 8;
    const int r = tid >> 3, sl = tid & 7;
    const int wr = w & 3, wc = w >> 2;

    for (int i = tid; i < 2048; i += 512) {
        uint4 v = ((const uint4*)Wt)[i];
        *(uint4*)&Wl[(i >> 4) * KP + (i & 15) * 8] = v;
    }

    for (int tile = blockIdx.x; tile < ntiles; tile += gridDim.x) {
        const int node0 = tile * 32;
        {
            int nl = r >> 1, b = r & 1;
            int node = min(node0 + nl, N - 1);
            int e0 = row_ptr[node], e1 = row_ptr[node + 1];
            float sc = invdeg[node];
            const u32* xb = (const u32*)xin + (size_t)b * 64 + sl * 8;
            h2 fa[8];
            h2 zz; zz[0] = (_Float16)0.f; zz[1] = (_Float16)0.f;
            #pragma unroll
            for (int j = 0; j < 8; ++j) fa[j] = zz;
            int e = e0;
            for (; e + 2 <= e1; e += 2) {
                int c0 = col_sorted[e], c1 = col_sorted[e + 1];
                const uint4* p0 = (const uint4*)(xb + (size_t)c0 * 128);
                const uint4* p1 = (const uint4*)(xb + (size_t)c1 * 128);
                uint4 u0 = p0[0], u1 = p0[1];
                uint4 w0 = p1[0], w1 = p1[1];
                const h2* h0 = (const h2*)&u0;
                const h2* h1 = (const h2*)&u1;
                const h2* g0 = (const h2*)&w0;
                const h2* g1 = (const h2*)&w1;
                #pragma unroll
                for (int j = 0; j < 4; ++j) {
                    fa[j]     += h0[j];
                    fa[4 + j] += h1[j];
                }
                #pragma unroll
                for (int j = 0; j < 4; ++j) {
                    fa[j]     += g0[j];
                    fa[4 + j] += g1[j];
                }
            }
            if (e < e1) {
                const uint4* p0 = (const uint4*)(xb + (size_t)col_sorted[e] * 128);
                uint4 u0 = p0[0], u1 = p0[1];
                const h2* h0 = (const h2*)&u0;
                const h2* h1 = (const h2*)&u1;
                #pragma unroll
                for (int j = 0; j < 4; ++j) {
                    fa[j]     += h0[j];
                    fa[4 + j] += h1[j];
                }
            }
            h2 scv; scv[0] = (_Float16)sc; scv[1] = (_Float16)sc;
            union { h2 h[4]; uint4 u; } P0, P1;
            #pragma unroll
            for (int j = 0; j < 4; ++j) {
                P0.h[j] = fa[j] * scv;
                P1.h[j] = fa[4 + j] * scv;
            }
            uint4* dst = (uint4*)&A[r * KP + sl * 16];
            dst[0] = P0.u;
            dst[1] = P1.u;
        }
        __syncthreads();

        const int arow = wr * 16 + l15;
        half8 a[4];
        #pragma unroll
        for (int kt = 0; kt < 4; ++kt)
            a[kt] = *(const half8*)&A[arow * KP + kt * 32 + kq];
        f32x4 acc[4];
        #pragma unroll
        for (int t = 0; t < 4; ++t) {
            int bcol = wc * 64 + t * 16 + l15;
            f32x4 c4 = {0.f, 0.f, 0.f, 0.f};
            #pragma unroll
            for (int kt = 0; kt < 4; ++kt) {
                half8 bfr = *(const half8*)&Wl[bcol * KP + kt * 32 + kq];
                c4 = __builtin_amdgcn_mfma_f32_16x16x32_f16(a[kt], bfr, c4, 0, 0, 0);
            }
            acc[t] = c4;
        }

        float s[4] = {0, 0, 0, 0}, sq[4] = {0, 0, 0, 0};
        #pragma unroll
        for (int t = 0; t < 4; ++t) {
            int col = wc * 64 + t * 16 + l15;
            float bt = bias[col];
            #pragma unroll
            for (int i = 0; i < 4; ++i) {
                float aY = acc[t][i] + bt;
                float y = aY / (1.0f + __expf(-aY));
                acc[t][i] = y;
                s[i] += y;
                sq[i] = fmaf(y, y, sq[i]);
            }
        }
        #pragma unroll
        for (int m = 1; m <= 8; m <<= 1) {
            #pragma unroll
            for (int i = 0; i < 4; ++i) {
                s[i] += __shfl_xor(s[i], m);
                sq[i] += __shfl_xor(sq[i], m);
            }
        }
        if (l15 == 0) {
            #pragma unroll
            for (int i = 0; i < 4; ++i) {
                int rr = wr * 16 + (lane >> 4) * 4 + i;
                pS[rr][wc] = s[i];
                pQ[rr][wc] = sq[i];
            }
        }
        __syncthreads();

        if (!fuse) {
            #pragma unroll
            for (int i = 0; i < 4; ++i) {
                int rr = wr * 16 + (lane >> 4) * 4 + i;
                float st = pS[rr][0] + pS[rr][1];
                float qt = pQ[rr][0] + pQ[rr][1];
                float mu = st * (1.0f / 128.0f);
                float var = qt * (1.0f / 128.0f) - mu * mu;
                float inv = rsqrtf(var + LN_EPS);
                if (node0 + (rr >> 1) < N) {
                    u16* xr = xout + ((size_t)node0 * 2 + rr) * 128;
                    #pragma unroll
                    for (int t = 0; t < 4; ++t) {
                        int col = wc * 64 + t * 16 + l15;
                        xr[col] = f2h((acc[t][i] - mu) * inv * gain[col] + beta[col]);
                    }
                }
            }
        } else {
            int gt0 = grp[node0];
            int gt1 = grp[min(node0 + 31, N - 1)];
            float gnr[4], btr2[4];
            #pragma unroll
            for (int t = 0; t < 4; ++t) {
                int col = wc * 64 + t * 16 + l15;
                gnr[t] = gain[col]; btr2[t] = beta[col];
            }
            float sb0[4] = {0, 0, 0, 0}, sb1[4] = {0, 0, 0, 0};
            if (gt0 == gt1) {
                #pragma unroll
                for (int i = 0; i < 4; ++i) {
                    int rr = wr * 16 + (lane >> 4) * 4 + i;
                    int node = node0 + (rr >> 1);
                    float st = pS[rr][0] + pS[rr][1];
                    float qt = pQ[rr][0] + pQ[rr][1];
                    float mu = st * (1.0f / 128.0f);
                    float var = qt * (1.0f / 128.0f) - mu * mu;
                    float inv = rsqrtf(var + LN_EPS);
                    float msk = (node < N) ? 1.f : 0.f;
                    #pragma unroll
                    for (int t = 0; t < 4; ++t) {
                        float y = ((acc[t][i] - mu) * inv * gnr[t] + btr2[t]) * msk;
                        if (i & 1) sb1[t] += y; else sb0[t] += y;
                    }
                }
                #pragma unroll
                for (int t = 0; t < 4; ++t) {
                    sb0[t] += __shfl_xor(sb0[t], 16); sb1[t] += __shfl_xor(sb1[t], 16);
                    sb0[t] += __shfl_xor(sb0[t], 32); sb1[t] += __shfl_xor(sb1[t], 32);
                }
            } else {
                #pragma unroll
                for (int i = 0; i < 4; ++i) {
                    int rr = wr * 16 + (lane >> 4) * 4 + i;
                    int node = node0 + (rr >> 1);
                    if (node < N) {
                        float st = pS[rr][0] + pS[rr][1];
                        float qt = pQ[rr][0] + pQ[rr][1];
                        float mu = st * (1.0f / 128.0f);
                        float var = qt * (1.0f / 128.0f) - mu * mu;
                        float inv = rsqrtf(var + LN_EPS);
                        int g = grp[node];
                        int b = rr & 1;
                        #pragma unroll
                        for (int t = 0; t < 4; ++t) {
                            int col = wc * 64 + t * 16 + l15;
                            float y = (acc[t][i] - mu) * inv * gnr[t] + btr2[t];
                            atomicAdd(&pooled[(g * B + b) * 128 + col], y);
                        }
                    }
                }
            }
            if ((lane >> 4) == 0) {
                float* w0p = wavesum + (((size_t)tile * 4 + wr) * 2 + 0) * 128;
                float* w1p = wavesum + (((size_t)tile * 4 + wr) * 2 + 1) * 128;
                #pragma unroll
                for (int t = 0; t < 4; ++t) {
                    int col = wc * 64 + t * 16 + l15;
                    w0p[col] = sb0[t];
                    w1p[col] = sb1[t];
                }
            }
        }
    }
}

// ---------------- pool reduce: wavesum -> pooled ----------------
__global__ __launch_bounds__(128) void k_pred(
    const float* __restrict__ wavesum, const int* __restrict__ gstart,
    float* __restrict__ pooled, int B, int G, int SPLIT, int ntiles)
{
    int blk = blockIdx.x;
    int split = blk % SPLIT;
    int gb = blk / SPLIT;
    int b = gb % B, g = gb / B;
    int col = threadIdx.x;
    int t0 = gstart[g] >> 5;
    int t1 = (gstart[g + 1] + 31) >> 5;
    if (t1 > ntiles) t1 = ntiles;
    int len = t1 - t0;
    int chunk = (len + SPLIT - 1) / SPLIT;
    int a0 = t0 + split * chunk;
    int a1 = min(t1, a0 + chunk);
    float s = 0.f;
    for (int t = a0; t < a1; ++t) {
        const float* wp = wavesum + ((size_t)t * 8 + b) * 128 + col;
        s += wp[0] + wp[256] + wp[512] + wp[768];
    }
    if (a1 > a0) atomicAdd(&pooled[(g * B + b) * 128 + col], s);
}

__global__ __launch_bounds__(128) void k_proj(
    const float* __restrict__ pooled, const float* __restrict__ Wp,
    const float* __restrict__ bp, float* __restrict__ out, int GB)
{
    int gb = blockIdx.x;
    int tid = threadIdx.x;
    float v = pooled[gb * 128 + tid] * Wp[tid];
    v += __shfl_down(v, 32);
    v += __shfl_down(v, 16);
    v += __shfl_down(v, 8);
    v += __shfl_down(v, 4);
    v += __shfl_down(v, 2);
    v += __shfl_down(v, 1);
    __shared__ float red[2];
    if ((tid & 63) == 0) red[tid >> 6] = v;
    __syncthreads();
    if (tid == 0) out[gb] = red[0] + red[1] + bp[0];
}

// ---------------- host ----------------
extern "C" void kernel_launch(void* const* d_in, const int* in_sizes, int n_in,
                              void* d_out, int out_size, void* d_ws, size_t ws_size,
                              hipStream_t stream) {
    const float* features = (const float*)d_in[0];
    const int* edge_index = (const int*)d_in[1];
    const int* lengths    = (const int*)d_in[2];
    const float* emb      = (const float*)d_in[3];
    const float* W_in     = (const float*)d_in[4];
    const float* b_in     = (const float*)d_in[5];
    const float* g_in     = (const float*)d_in[6];
    const float* beta_in  = (const float*)d_in[7];
    const float* msg_W    = (const float*)d_in[8];
    const float* msg_b    = (const float*)d_in[9];
    const float* msg_g    = (const float*)d_in[10];
    const float* msg_beta = (const float*)d_in[11];
    const float* W_proj   = (const float*)d_in[12];
    const float* b_proj   = (const float*)d_in[13];
    float* out = (float*)d_out;

    const int E = in_sizes[1] / 2;
    const int G = in_sizes[2];
    const int B = out_size / G;
    const int C = in_sizes[5];           // 128
    const int F = 128;
    const int N = in_sizes[0] / (B * F);
    const int M = B * N;
    const int L = in_sizes[9] / C;       // 3

    const int* rows = edge_index;
    const int* cols = edge_index + E;

    // workspace carve-up (16B-aligned)
    u16* buf0   = (u16*)d_ws;                               // M*128 (interleaved [n][b][c])
    u16* buf1   = buf0 + (size_t)M * 128;                   // M*128
    u16* Wt_in  = buf1 + (size_t)M * 128;                   // 128*128
    u16* Wt_msg = Wt_in + 128 * 128;                        // 3*128*128
    float* E_proj = (float*)(Wt_msg + 3 * 128 * 128);       // 128*128 f32
    float* invdeg = E_proj + 128 * 128;                     // N
    int*   deg    = (int*)(invdeg + N);                     // N (reused as cursor)
    float* pooled = (float*)(deg + N);                      // G*B*128
    int*   row_ptr = (int*)(pooled + (size_t)G * B * 128);  // N+1
    int*   col_sorted = row_ptr + N + 1;                    // E
    int*   bsum   = col_sorted + E;                         // ~64
    int*   gstart = bsum + 64;                              // G+1
    int*   grp    = gstart + G + 1;                         // N
    float* wavesum = (float*)(grp + N);                     // ntiles*8*128

    const int nb_scan = (N + SCAN_ELEMS - 1) / SCAN_ELEMS;
    const int nt32 = (N + 31) / 32;
    const int grid_mp = nt32 < 1024 ? nt32 : 1024;

    // weight prep
    {
        int total = 4 * 128 * 128;
        k_wprep<<<(total + 255) / 256, 256, 0, stream>>>(W_in, msg_W, Wt_in, Wt_msg);
        k_eproj<<<128, 128, 0, stream>>>(W_in, emb, E_proj);
    }

    // degree + CSR + group map
    hipMemsetAsync(deg, 0, (size_t)N * sizeof(int), stream);
    hipMemsetAsync(pooled, 0, (size_t)G * B * 128 * sizeof(float), stream);
    k_deg<<<(E + 255) / 256, 256, 0, stream>>>(rows, deg, E);
    k_invdeg<<<(N + 255) / 256, 256, 0, stream>>>(deg, invdeg, N);
    k_scan1<<<nb_scan, SCAN_T, 0, stream>>>(deg, row_ptr, bsum, N);
    k_scan2<<<1, 1, 0, stream>>>(bsum, nb_scan, row_ptr, N);
    k_scan3<<<nb_scan, SCAN_T, 0, stream>>>(row_ptr, bsum, N);
    k_copy_cursor<<<(N + 255) / 256, 256, 0, stream>>>(row_ptr, deg, N);
    k_bucket<<<(E + 255) / 256, 256, 0, stream>>>(rows, cols, deg, col_sorted, E);
    k_gstart<<<1, 1, 0, stream>>>(lengths, gstart, G);
    k_grp<<<(N + 255) / 256, 256, 0, stream>>>(gstart, grp, N, G);

    // input layer -> buf0 (interleaved)
    k_input_mfma<<<grid_mp, 512, 0, stream>>>(features, E_proj, Wt_in,
                                              b_in, g_in, beta_in, buf0, N, nt32);

    // fused mp layers (ping-pong); last layer fuses pooling via wavesum scratch
    u16* bufs[2] = {buf0, buf1};
    int cur = 0;
    for (int l = 0; l < L; ++l) {
        int fuse = (l == L - 1) ? 1 : 0;
        k_mp_mfma<<<grid_mp, 512, 0, stream>>>(row_ptr, col_sorted, invdeg,
                                               bufs[cur], Wt_msg + (size_t)l * 128 * 128,
                                               msg_b + (size_t)l * C, msg_g + (size_t)l * C,
                                               msg_beta + (size_t)l * C,
                                               bufs[1 - cur], grp, pooled, wavesum,
                                               fuse, N, B, nt32);
        cur = 1 - cur;
    }

    // pool reduce + projection
    const int SPLIT = 32;
    k_pred<<<G * B * SPLIT, 128, 0, stream>>>(wavesum, gstart, pooled, B, G, SPLIT, nt32);
    k_proj<<<G * B, 128, 0, stream>>>(pooled, W_proj, b_proj, out, G * B);
}